// Round 12
// baseline (449.665 us; speedup 1.0000x reference)
//
#include <hip/hip_runtime.h>
#include <hip/hip_bf16.h>
#include <hip/hip_fp16.h>
#include <math.h>

using bf16 = __hip_bfloat16;

typedef __attribute__((ext_vector_type(8))) short v8s;   // 8 bf16 = 4 VGPRs
typedef __attribute__((ext_vector_type(4))) short v4s;   // 4 bf16 = 2 VGPRs
typedef __attribute__((ext_vector_type(4))) float v4f;   // MFMA accumulator

// Problem constants
constexpr int kB   = 2;
constexpr int kL   = 1024;
constexpr int kD   = 512;    // d_model
constexpr int kDI  = 1024;   // inner dim
constexpr int kNS  = 16;     // d_state
constexpr int kDTR = 32;     // dt_rank
constexpr int kKC  = 4;      // conv width
constexpr int kNC  = 8;      // clusters
constexpr int kM   = kB * kL;  // 2048 rows
constexpr int kCH  = 32;       // scan chunks
constexpr int kCL  = kL / kCH; // 32 steps per chunk
constexpr float kEPS = 1e-5f;

static __device__ __forceinline__ float toF(bf16 x) { return __bfloat162float(x); }
static __device__ __forceinline__ float b2f(short u) {
    unsigned int x = ((unsigned int)(unsigned short)u) << 16;
    return __uint_as_float(x);
}

// flag-dispatched raw-input load: flag=1 -> fp32, flag=0 -> bf16
static __device__ __forceinline__ float ldin(const void* p, int i, int f32) {
    if (f32) return ((const float*)p)[i];
    return toF(((const bf16*)p)[i]);
}

static __device__ __forceinline__ int flipL(int r) { return r ^ (kL - 1); }

// ---------------- block reduce (256 threads = 4 waves) ----------------
static __device__ __forceinline__ float blockReduceSum(float v, float* s) {
    __syncthreads();
#pragma unroll
    for (int o = 32; o > 0; o >>= 1) v += __shfl_down(v, o, 64);
    int lane = threadIdx.x & 63, wid = threadIdx.x >> 6;
    if (lane == 0) s[wid] = v;
    __syncthreads();
    if (threadIdx.x == 0) {
        float t = 0.f;
        for (int i = 0; i < 4; ++i) t += s[i];
        s[4] = t;
    }
    __syncthreads();
    return s[4];
}

// per-block dtype probe: 0 = bf16, 1 = f32 (all threads get result)
static __device__ __forceinline__ int detect_local(const unsigned short* x, float* sred) {
    float c = 0.f;
    for (int i = threadIdx.x; i < 512; i += 256) {
        unsigned short h = x[2 * i];  // even (low) halves
        int e = (h >> 7) & 0xFF;
        if (e >= 100 && e <= 140) c += 1.f;
    }
    float tot = blockReduceSum(c, sred);
    return (tot >= 256.f) ? 0 : 1;
}

// ---------------- fused setup: weight conversion + anT + cnorm + flag + input LN ----------------
// grid (512, 17). y<12: wconv tile y. y==12: x<128 anT; x in [128,136) cnorm; x==136 flag.
// y in 13..16: LayerNorm of input row (y-13)*512 + x -> xn.
struct WSrcs { const void* p[12]; };

__global__ __launch_bounds__(256) void setup_kernel(WSrcs s, bf16* __restrict__ dst,
                                                    const void* __restrict__ alog_f,
                                                    const void* __restrict__ alog_b,
                                                    const void* __restrict__ centers,
                                                    float* __restrict__ anT,
                                                    float* __restrict__ cn,
                                                    int* __restrict__ flag,
                                                    const void* __restrict__ X,
                                                    const void* __restrict__ n1g,
                                                    const void* __restrict__ n1b,
                                                    bf16* __restrict__ xn) {
    __shared__ float sred[8];
    int f32 = detect_local((const unsigned short*)X, sred);
    int t = blockIdx.y;
    if (t < 12) {
        const int sz[12]  = {1048576, 1048576, 65536, 65536, 32768, 32768,
                             524288, 524288, 524288, 262144, 1048576, 1048576};
        const int off[12] = {0, 1048576, 2097152, 2162688, 2228224, 2260992,
                             2293760, 2818048, 3342336, 3866624, 4128768, 5177344};
        int n = sz[t];
        const void* src = s.p[t];
        bf16* d = dst + off[t];
        for (int i = blockIdx.x * 256 + threadIdx.x; i < n; i += 512 * 256)
            d[i] = __float2bfloat16(ldin(src, i, f32));
    } else if (t == 12) {
        int bx = blockIdx.x;
        if (bx < 128) {
            int tid = bx * 256 + threadIdx.x;  // 32768
            int d = tid & (kDI - 1);
            int n = (tid >> 10) & (kNS - 1);
            int dir = tid >> 14;
            anT[tid] = -__expf(ldin(dir ? alog_b : alog_f, d * kNS + n, f32));
        } else if (bx < 136) {
            int c = bx - 128;
            float ssum = 0.f;
            for (int i = threadIdx.x; i < kD; i += 256) {
                float v = ldin(centers, c * kD + i, f32);
                ssum += v * v;
            }
            float tot = blockReduceSum(ssum, sred);
            if (threadIdx.x == 0) cn[c] = sqrtf(tot);
        } else if (bx == 136) {
            if (threadIdx.x == 0) *flag = f32;
        }
    } else {
        // input LayerNorm, one block per row
        int row = (t - 13) * 512 + blockIdx.x;
        int i = threadIdx.x;
        size_t base = (size_t)row * kD;
        float x0 = ldin(X, base + i, f32), x1 = ldin(X, base + i + 256, f32);
        float mean = blockReduceSum(x0 + x1, sred) * (1.f / kD);
        float vs = blockReduceSum(x0 * x0 + x1 * x1, sred) * (1.f / kD) - mean * mean;
        float rstd = rsqrtf(vs + kEPS);
        xn[base + i]       = __float2bfloat16((x0 - mean) * rstd * ldin(n1g, i, f32)       + ldin(n1b, i, f32));
        xn[base + i + 256] = __float2bfloat16((x1 - mean) * rstd * ldin(n1g, i + 256, f32) + ldin(n1b, i + 256, f32));
    }
}

// ---------------- MFMA bf16 GEMM with z-batch + global_load_lds + XOR-swizzled LDS ----------------
template <int BM, int BN, int WRN, int WCN>
__global__ __launch_bounds__(256) void mfma_gemm(const bf16* __restrict__ A, int lda, int aZOff,
                                                 const bf16* __restrict__ W, int K, int wZOff,
                                                 const void* __restrict__ bias, int act,
                                                 const float* __restrict__ resid,
                                                 bf16* __restrict__ outB,
                                                 void* __restrict__ outRaw,
                                                 int ldo, int oZOff,
                                                 int flipN0, int zflip,
                                                 const int* __restrict__ flg,
                                                 bf16* __restrict__ outSplitZ,
                                                 const bf16* __restrict__ wCcp,
                                                 const void* __restrict__ ccpBias,
                                                 bf16* __restrict__ outCcp,
                                                 int nSplit2) {
    __shared__ bf16 As[BM * 64];
    __shared__ bf16 Bs[BN * 64];
    constexpr int FR = BM / WRN / 16;
    constexpr int FC = BN / WCN / 16;
    constexpr int AV = BM / 32;  // 16B chunks per thread for A tile
    constexpr int BV = BN / 32;

    int f32 = *flg;
    int tid = threadIdx.x;
    int z = blockIdx.z;
    const bf16* Ab = A + (size_t)z * aZOff;
    int m0 = blockIdx.y * BM, n0 = blockIdx.x * BN;
    const bf16* Wb = W + (size_t)z * wZOff;
    int nrow0 = n0;
    bool isCcp = (wCcp != nullptr) && (n0 >= nSplit2);
    if (isCcp) { Wb = wCcp; nrow0 = n0 - nSplit2; }
    int lane = tid & 63, w = tid >> 6;
    int wr = w % WRN, wc = w / WRN;
    int rbase = wr * (BM / WRN), cbase = wc * (BN / WCN);
    int quad = lane >> 4, lrow = lane & 15;
    int wbase = tid & ~63;  // wave-uniform

    v4f acc[FR][FC];
#pragma unroll
    for (int i = 0; i < FR; ++i)
#pragma unroll
        for (int j = 0; j < FC; ++j)
#pragma unroll
            for (int r = 0; r < 4; ++r) acc[i][j][r] = 0.f;

    for (int kt = 0; kt < K; kt += 64) {
#pragma unroll
        for (int i = 0; i < AV; ++i) {
            int v = i * 256 + tid;
            int row = v >> 3;
            int c8 = ((v & 7) * 8) ^ ((row & 7) * 8);  // swizzled source chunk
            const bf16* gp = Ab + (size_t)(m0 + row) * lda + kt + c8;
            __builtin_amdgcn_global_load_lds(
                (const __attribute__((address_space(1))) void*)gp,
                (__attribute__((address_space(3))) void*)&As[(i * 256 + wbase) * 8],
                16, 0, 0);
        }
#pragma unroll
        for (int i = 0; i < BV; ++i) {
            int v = i * 256 + tid;
            int row = v >> 3;
            int c8 = ((v & 7) * 8) ^ ((row & 7) * 8);
            const bf16* gp = Wb + (size_t)(nrow0 + row) * K + kt + c8;
            __builtin_amdgcn_global_load_lds(
                (const __attribute__((address_space(1))) void*)gp,
                (__attribute__((address_space(3))) void*)&Bs[(i * 256 + wbase) * 8],
                16, 0, 0);
        }
        __syncthreads();
#pragma unroll
        for (int k0 = 0; k0 < 64; k0 += 32) {
            v8s a[FR], b[FC];
#pragma unroll
            for (int fr = 0; fr < FR; ++fr) {
                int r = rbase + fr * 16 + lrow;
                a[fr] = *reinterpret_cast<const v8s*>(
                    &As[r * 64 + ((k0 + quad * 8) ^ ((r & 7) * 8))]);
            }
#pragma unroll
            for (int fc = 0; fc < FC; ++fc) {
                int r = cbase + fc * 16 + lrow;
                b[fc] = *reinterpret_cast<const v8s*>(
                    &Bs[r * 64 + ((k0 + quad * 8) ^ ((r & 7) * 8))]);
            }
#pragma unroll
            for (int fr = 0; fr < FR; ++fr)
#pragma unroll
                for (int fc = 0; fc < FC; ++fc)
                    acc[fr][fc] = __builtin_amdgcn_mfma_f32_16x16x32_bf16(a[fr], b[fc], acc[fr][fc], 0, 0, 0);
        }
        __syncthreads();
    }

    // epilogue: C/D layout col=lane&15, row=quad*4+reg  [m89-verified]
    bf16* outBz = outB ? outB + (size_t)z * oZOff : nullptr;
#pragma unroll
    for (int fr = 0; fr < FR; ++fr) {
#pragma unroll
        for (int fc = 0; fc < FC; ++fc) {
            int ncol = n0 + cbase + fc * 16 + lrow;
            float bi = bias ? ldin(bias, ncol, f32) : 0.f;
            bool doflip = (ncol >= flipN0) || (zflip && z == 1);
#pragma unroll
            for (int r = 0; r < 4; ++r) {
                int m = m0 + rbase + fr * 16 + quad * 4 + r;
                float vv = acc[fr][fc][r] + bi;
                if (act == 2) vv = 0.5f * vv * (1.f + erff(vv * 0.70710678118654752440f));
                if (resid) vv += resid[(size_t)m * ldo + ncol];
                if (outCcp && ncol >= nSplit2) {
                    float v2 = vv + ldin(ccpBias, ncol - nSplit2, f32);
                    outCcp[(size_t)m * kD + (ncol - nSplit2)] = __float2bfloat16(v2);
                } else if (outSplitZ) {
                    int dir = (ncol >> 11) & 1;
                    int isz = (ncol >> 10) & 1;
                    int c2 = dir * 1024 + (ncol & 1023);
                    int mo_ = dir ? flipL(m) : m;
                    bf16* dst = isz ? outSplitZ : outB;
                    dst[(size_t)mo_ * 2048 + c2] = __float2bfloat16(vv);
                } else {
                    int mo_ = doflip ? flipL(m) : m;
                    size_t oi = (size_t)mo_ * ldo + ncol;
                    if (outBz) outBz[oi] = __float2bfloat16(vv);
                    else if (f32) ((float*)outRaw)[oi] = vv;
                    else ((bf16*)outRaw)[oi] = __float2bfloat16(vv);
                }
            }
        }
    }
}

// ---------------- depthwise causal conv + silu, both dirs ----------------
__global__ __launch_bounds__(256) void conv_kernel(const bf16* __restrict__ xp,
                                                   const void* __restrict__ cw_f,
                                                   const void* __restrict__ cb_f,
                                                   const void* __restrict__ cw_b,
                                                   const void* __restrict__ cb_b,
                                                   bf16* __restrict__ xc,
                                                   const int* __restrict__ flg) {
    int f32 = *flg;
    int tid = blockIdx.x * 256 + threadIdx.x;  // 2*kM*kDI
    int d = tid & (kDI - 1);
    int r = (tid >> 10) & (kM - 1);
    int dir = tid >> 21;
    int l = r & (kL - 1);
    int b = r >> 10;
    const void* cw = dir ? cw_b : cw_f;
    const void* cb = dir ? cb_b : cb_f;
    float acc = ldin(cb, d, f32);
#pragma unroll
    for (int k = 0; k < kKC; ++k) {
        int ll = l - (kKC - 1) + k;
        if (ll >= 0)
            acc += ldin(cw, d * kKC + k, f32) *
                   toF(xp[(size_t)(b * kL + ll) * (2 * kDI) + dir * kDI + d]);
    }
    float s = acc / (1.f + __expf(-acc));
    xc[(size_t)r * (2 * kDI) + dir * kDI + d] = __float2bfloat16(s);
}

// ---------------- fused xproj + delta: one block per row m ----------------
// xdbl row = [dt_f|B_f|C_f | dt_b|B_b|C_b] (128), delta = softplus(dt @ wdt^T + dtb).
// Replaces the grid-starved MFMA xproj (128 blocks) + delta_kernel.
__global__ __launch_bounds__(256) void xproj_delta_kernel(
    const bf16* __restrict__ xc,      // 2048 x 2048
    const bf16* __restrict__ w_xp,    // 2 x (64 x 1024)
    const bf16* __restrict__ w_dt,    // 2 x (1024 x 32)
    const void* __restrict__ dtb_f,
    const void* __restrict__ dtb_b,
    bf16* __restrict__ xdbl,          // 2048 x 128
    __half* __restrict__ deltaH,      // 2 x 2048 x 1024
    const int* __restrict__ flg) {
    __shared__ bf16 xrow[2 * kDI];
    __shared__ float xd[128];
    int f32 = *flg;
    int m = blockIdx.x;
    int t = threadIdx.x;
    // stage xc row (4 KB) into LDS
    {
        v8s v = *reinterpret_cast<const v8s*>(xc + (size_t)m * (2 * kDI) + t * 8);
        *reinterpret_cast<v8s*>(&xrow[t * 8]) = v;
    }
    __syncthreads();
    // xproj: output o = t>>1 (0..127), half = t&1 covers K/2 = 512
    {
        int o = t >> 1, half = t & 1;
        int dir = o >> 6, n = o & 63;
        const bf16* wrow = w_xp + ((size_t)dir * 64 + n) * kDI + half * 512;
        const bf16* xsrc = &xrow[dir * kDI + half * 512];
        float p = 0.f;
#pragma unroll 8
        for (int k = 0; k < 512; k += 8) {
            v8s wv = *reinterpret_cast<const v8s*>(wrow + k);
            v8s xv = *reinterpret_cast<const v8s*>(xsrc + k);
#pragma unroll
            for (int j = 0; j < 8; ++j) p += b2f(xv[j]) * b2f(wv[j]);
        }
        p += __shfl_xor(p, 1);
        if (half == 0) {
            xd[o] = p;
            xdbl[(size_t)m * 128 + o] = __float2bfloat16(p);
        }
    }
    __syncthreads();
    // delta: 2 dirs x 1024 d
    for (int i = t; i < 2 * kDI; i += 256) {
        int dir = i >> 10, d = i & (kDI - 1);
        float acc = ldin(dir ? dtb_b : dtb_f, d, f32);
        const bf16* wrow = w_dt + ((size_t)dir * kDI + d) * kDTR;
        const float* xsrc = &xd[dir * 64];
#pragma unroll
        for (int kk = 0; kk < kDTR; kk += 8) {
            v8s wv = *reinterpret_cast<const v8s*>(wrow + kk);
#pragma unroll
            for (int j = 0; j < 8; ++j) acc += xsrc[kk + j] * b2f(wv[j]);
        }
        acc = (acc > 20.f) ? acc : log1pf(__expf(acc));
        deltaH[((size_t)dir * kM + m) * kDI + d] = __float2half(acc);
    }
}

// ---------------- fused local scan: y_local + chunk summaries + cumsum(dl) ----------------
// tid bits: [1:0]=n4, [11:2]=d, [16:12]=c, [17]=b, [18]=dir  (524288 threads)
// PA/HLh layout is d-innermost: [((g*kCH + c)*kNS + n)*kDI + d], g = dir*2+b.
__global__ __launch_bounds__(256) void scan_phase1(const bf16* __restrict__ xc,
                                                   const bf16* __restrict__ xdbl,
                                                   __half* __restrict__ deltaS,
                                                   const float* __restrict__ anT,
                                                   float* __restrict__ PA,
                                                   __half* __restrict__ HLh,
                                                   bf16* __restrict__ ymul,
                                                   const int* __restrict__ flg) {
    int tid = blockIdx.x * 256 + threadIdx.x;
    int n4  = tid & 3;
    int d   = (tid >> 2) & (kDI - 1);
    int c   = (tid >> 12) & (kCH - 1);
    int b   = (tid >> 17) & 1;
    int dir = tid >> 18;
    float an[4], h[4], pa[4];
#pragma unroll
    for (int j = 0; j < 4; ++j) {
        an[j] = anT[((size_t)dir * kNS + n4 * 4 + j) * kDI + d];
        h[j] = 0.f;
        pa[j] = 1.f;
    }
    __half* dptr = deltaS + ((size_t)dir * kM + (size_t)b * kL) * kDI + d;
    float s = 0.f;
    int l0 = c * kCL;
    for (int l = l0; l < l0 + kCL; ++l) {
        size_t rb = (size_t)b * kL + l;
        float dl = __half2float(dptr[(size_t)l * kDI]);
        s += dl;
        float xcv = toF(xc[rb * (2 * kDI) + dir * kDI + d]);
        float du = dl * xcv;
        v4s Bv = *reinterpret_cast<const v4s*>(xdbl + rb * 128 + dir * 64 + kDTR + n4 * 4);
        v4s Cv = *reinterpret_cast<const v4s*>(xdbl + rb * 128 + dir * 64 + kDTR + kNS + n4 * 4);
        float yp = 0.f;
#pragma unroll
        for (int j = 0; j < 4; ++j) {
            float a = __expf(dl * an[j]);
            pa[j] *= a;
            h[j] = a * h[j] + du * b2f(Bv[j]);
            yp += h[j] * b2f(Cv[j]);
        }
        yp += __shfl_xor(yp, 1);
        yp += __shfl_xor(yp, 2);
        if (n4 == 0) {
            ymul[rb * (2 * kDI) + dir * kDI + d] = __float2bfloat16(yp);
            dptr[(size_t)l * kDI] = __float2half(s);  // in-place: all lanes read dl above first
        }
    }
    int g = dir * kB + b;
    size_t o = (((size_t)g * kCH + c) * kNS + n4 * 4) * kDI + d;
#pragma unroll
    for (int j = 0; j < 4; ++j) {
        PA[o + (size_t)j * kDI] = pa[j];
        HLh[o + (size_t)j * kDI] = __float2half(h[j]);
    }
}

// combine over chunks; write HIN (incoming state per chunk) in-place into PA
// tid bits: [9:0]=d, [13:10]=n, [15:14]=g  (65536 threads) — d-innermost -> coalesced
__global__ __launch_bounds__(256) void scan_phase2(float* __restrict__ PA,
                                                   const __half* __restrict__ HLh) {
    int tid = blockIdx.x * 256 + threadIdx.x;
    int d = tid & (kDI - 1);
    int n = (tid >> 10) & (kNS - 1);
    int g = tid >> 14;
    float h = 0.f;
    for (int c = 0; c < kCH; ++c) {
        size_t idx = (((size_t)g * kCH + c) * kNS + n) * kDI + d;
        float pav = PA[idx];
        float hlv = __half2float(HLh[idx]);
        PA[idx] = h;  // HIN for chunk c
        h = pav * h + hlv;
    }
}

// ---------------- parallel correction: y = y_local + C.(exp(an*s) * h_in) + xc*D, gate silu(z) ----------------
// tid bits: [9:0]=d, [19:10]=l, [20]=b, [21]=dir  (4,194,304 threads)
__global__ __launch_bounds__(256) void scan_fix(const bf16* __restrict__ xc,
                                                const bf16* __restrict__ xdbl,
                                                const bf16* __restrict__ zb,
                                                const __half* __restrict__ sbuf,
                                                const float* __restrict__ anT,
                                                const void* __restrict__ dp_f,
                                                const void* __restrict__ dp_b,
                                                const float* __restrict__ HIN,
                                                bf16* __restrict__ ymul,
                                                const int* __restrict__ flg) {
    int f32 = *flg;
    int tid = blockIdx.x * 256 + threadIdx.x;
    int d   = tid & (kDI - 1);
    int l   = (tid >> 10) & (kL - 1);
    int b   = (tid >> 20) & 1;
    int dir = tid >> 21;
    int c   = l / kCL;
    size_t rb = (size_t)b * kL + l;
    float s = __half2float(sbuf[((size_t)dir * kM + rb) * kDI + d]);
    int g = dir * kB + b;
    const float* hin = HIN + (((size_t)g * kCH + c) * kNS) * kDI + d;
    const float* anp = anT + (size_t)dir * kNS * kDI + d;
    const bf16* Cp = xdbl + rb * 128 + dir * 64 + kDTR + kNS;
    float ycorr = 0.f;
#pragma unroll
    for (int n = 0; n < kNS; ++n) {
        float an = anp[(size_t)n * kDI];
        ycorr += toF(Cp[n]) * __expf(an * s) * hin[(size_t)n * kDI];
    }
    size_t yi = rb * (2 * kDI) + dir * kDI + d;
    float xcv = toF(xc[yi]);
    float Dv = ldin(dir ? dp_b : dp_f, d, f32);
    float y = toF(ymul[yi]) + ycorr + xcv * Dv;
    float zv = toF(zb[yi]);
    float sz = zv / (1.f + __expf(-zv));
    ymul[yi] = __float2bfloat16(y * sz);
}

// ---------------- fused context-cluster + gate + residual + FFN-LN ----------------
__global__ __launch_bounds__(256) void post_kernel(const bf16* __restrict__ proj,
                                                   const void* __restrict__ centers,
                                                   const float* __restrict__ cn,
                                                   const bf16* __restrict__ xn,
                                                   const void* __restrict__ alpha_p,
                                                   const void* __restrict__ ccg,
                                                   const void* __restrict__ ccb,
                                                   const void* __restrict__ X,
                                                   const bf16* __restrict__ mo,
                                                   const void* __restrict__ gw,
                                                   const void* __restrict__ gb,
                                                   const void* __restrict__ fg,
                                                   const void* __restrict__ fbb,
                                                   float* __restrict__ xmid,
                                                   bf16* __restrict__ hln,
                                                   const int* __restrict__ flg) {
    __shared__ float sred[8];
    __shared__ float sims[kNC];
    int f32 = *flg;
    int row = blockIdx.x;
    int i = threadIdx.x;
    size_t base = (size_t)row * kD;
    float p0 = toF(proj[base + i]), p1 = toF(proj[base + i + 256]);
    float sumsq = blockReduceSum(p0 * p0 + p1 * p1, sred);
    float pn = fmaxf(sqrtf(sumsq), 1e-12f);
    for (int c = 0; c < kNC; ++c) {
        float part = p0 * ldin(centers, c * kD + i, f32) + p1 * ldin(centers, c * kD + i + 256, f32);
        float dot = blockReduceSum(part, sred);
        if (threadIdx.x == 0) sims[c] = dot / (pn * fmaxf(cn[c], 1e-12f));
    }
    __syncthreads();
    float mx = -1e30f;
#pragma unroll
    for (int c = 0; c < kNC; ++c) mx = fmaxf(mx, sims[c]);
    float wv[kNC], se = 0.f;
#pragma unroll
    for (int c = 0; c < kNC; ++c) { wv[c] = __expf(sims[c] - mx); se += wv[c]; }
    float inv = 1.f / se;
    float ctx0 = 0.f, ctx1 = 0.f;
#pragma unroll
    for (int c = 0; c < kNC; ++c) {
        float wc = wv[c] * inv;
        ctx0 += wc * ldin(centers, c * kD + i, f32);
        ctx1 += wc * ldin(centers, c * kD + i + 256, f32);
    }
    float alpha = ldin(alpha_p, 0, f32);
    float x0 = toF(xn[base + i]), x1 = toF(xn[base + i + 256]);
    float t0 = x0 + alpha * ctx0;
    float t1 = x1 + alpha * ctx1;
    float mean = blockReduceSum(t0 + t1, sred) * (1.f / kD);
    float vs = blockReduceSum(t0 * t0 + t1 * t1, sred) * (1.f / kD) - mean * mean;
    float rstd = rsqrtf(vs + kEPS);
    float cc0 = (t0 - mean) * rstd * ldin(ccg, i, f32)       + ldin(ccb, i, f32);
    float cc1 = (t1 - mean) * rstd * ldin(ccg, i + 256, f32) + ldin(ccb, i + 256, f32);
    // gate
    float d0 = blockReduceSum(x0 * ldin(gw, i, f32) + x1 * ldin(gw, i + 256, f32), sred);
    float d1 = blockReduceSum(x0 * ldin(gw, kD + i, f32) + x1 * ldin(gw, kD + i + 256, f32), sred);
    d0 += ldin(gb, 0, f32);
    d1 += ldin(gb, 1, f32);
    float gmx = fmaxf(d0, d1);
    float e0 = __expf(d0 - gmx), e1 = __expf(d1 - gmx);
    float gs = e0 + e1;
    float g0 = e0 / gs, g1 = e1 / gs;
    float xm0 = ldin(X, base + i, f32)       + g0 * toF(mo[base + i])       + g1 * cc0;
    float xm1 = ldin(X, base + i + 256, f32) + g0 * toF(mo[base + i + 256]) + g1 * cc1;
    xmid[base + i] = xm0;
    xmid[base + i + 256] = xm1;
    // FFN LayerNorm
    float mean2 = blockReduceSum(xm0 + xm1, sred) * (1.f / kD);
    float vs2 = blockReduceSum(xm0 * xm0 + xm1 * xm1, sred) * (1.f / kD) - mean2 * mean2;
    float rstd2 = rsqrtf(vs2 + kEPS);
    hln[base + i]       = __float2bfloat16((xm0 - mean2) * rstd2 * ldin(fg, i, f32)       + ldin(fbb, i, f32));
    hln[base + i + 256] = __float2bfloat16((xm1 - mean2) * rstd2 * ldin(fg, i + 256, f32) + ldin(fbb, i + 256, f32));
}

// ---------------- launch ----------------
extern "C" void kernel_launch(void* const* d_in, const int* in_sizes, int n_in,
                              void* d_out, int out_size, void* d_ws, size_t ws_size,
                              hipStream_t stream) {
    bool sig = (n_in > 3 && in_sizes[3] == 2 * kDI * kD);
    int I_fusion_w = sig ? 21 : 3,  I_fusion_b = sig ? 22 : 4;
    int I_centers  = sig ? 23 : 5,  I_ccp_w    = sig ? 24 : 6,  I_ccp_b = sig ? 25 : 7;
    int I_ccn_g    = sig ? 26 : 8,  I_ccn_b    = sig ? 27 : 9,  I_alpha = sig ? 28 : 10;
    int I_gate_w   = sig ? 29 : 11, I_gate_b   = sig ? 30 : 12;
    int I_ffn_g    = sig ? 31 : 13, I_ffn_b    = sig ? 32 : 14;
    int I_ffn_w1   = sig ? 33 : 15, I_ffn_b1   = sig ? 34 : 16;
    int I_ffn_w2   = sig ? 35 : 17, I_ffn_b2   = sig ? 36 : 18;
    int I_fm       = sig ? 3  : 19, I_bm       = sig ? 12 : 28;

    const void* X        = d_in[0];
    const void* n1g      = d_in[1];
    const void* n1b      = d_in[2];
    const void* fusion_b = d_in[I_fusion_b];
    const void* centers  = d_in[I_centers];
    const void* ccp_b    = d_in[I_ccp_b];
    const void* ccn_g    = d_in[I_ccn_g];
    const void* ccn_b    = d_in[I_ccn_b];
    const void* cc_alpha = d_in[I_alpha];
    const void* gate_w   = d_in[I_gate_w];
    const void* gate_b   = d_in[I_gate_b];
    const void* ffn_g    = d_in[I_ffn_g];
    const void* ffn_b    = d_in[I_ffn_b];
    const void* ffn_b1   = d_in[I_ffn_b1];
    const void* ffn_b2   = d_in[I_ffn_b2];

    // ---- workspace layout (float units) — total ~63.4 MB ----
    float* ws = (float*)d_ws;
    int* flg  = (int*)d_ws;           // ws[0]
    float* cn = ws + 8;               // 8 floats
    float*  anT  = ws + 32;                          // 32,768 f  (2 x 16 x 1024)
    float*  PA   = anT + 32768;                      // 2,097,152 f (d-innermost chunk summaries -> HIN)
    __half* HLh  = (__half*)(PA + 2097152);          // 2,097,152 half = 1,048,576 f
    bf16*  xn   = (bf16*)((float*)HLh + 1048576);    // 2048x512 bf16   = 524,288 f
    bf16*  xp   = (bf16*)((float*)xn + 524288);      // 2048x2048 bf16  = 2,097,152 f
    bf16*  zb   = (bf16*)((float*)xp + 2097152);     // 2048x2048 bf16  = 2,097,152 f
    bf16*  xc   = (bf16*)((float*)zb + 2097152);     // 2048x2048 bf16  = 2,097,152 f
    bf16*  xdbl = (bf16*)((float*)xc + 2097152);     // 2048x128 bf16   = 131,072 f
    bf16*  ymul = (bf16*)((float*)xdbl + 131072);    // 2048x2048 bf16  = 2,097,152 f
    bf16*  wbuf = (bf16*)((float*)ymul + 2097152);   // 6,225,920 bf16  = 3,112,960 f
    bf16*  projb = (bf16*)((float*)wbuf + 3112960);  // 2048x512 bf16   = 524,288 f (dedicated)
    // aliases of dead regions (size-checked):
    __half* deltaH = (__half*)xp;    // 4,194,304 half exact (xp dead after conv); becomes s(l) after phase1
    bf16*  fb    = (bf16*)HLh;       // 2,097,152 bf16 exact (HLh dead after phase2; out_proj writes later)
    bf16*  mo    = (bf16*)PA;        // 524,288 f <= PA (HIN dead after scan_fix; fusion writes later)
    float* xmid  = PA + 524288;      // 1,048,576 f, disjoint from mo, within PA region (2M)
    bf16*  hln   = xc;               // after scan_fix
    bf16*  ffnh  = zb;               // after scan_fix (2M f exact)

    // weight views (order: fm_in, bm_in, fm_xproj, bm_xproj, fm_dt, bm_dt, fm_out, bm_out, fusion, ccp, ffn1, ffn2)
    bf16* w_in     = wbuf + 0;        // [fm|bm] concat, N=4096 x K=512
    bf16* w_xp     = wbuf + 2097152;  // 2 x (64 x 1024)
    bf16* w_dt     = wbuf + 2228224;  // 2 x (1024 x 32)
    bf16* w_out    = wbuf + 2293760;  // 2 x (512 x 1024)
    bf16* w_fusion = wbuf + 3342336;
    bf16* w_ccp    = wbuf + 3866624;
    bf16* w_ffn1   = wbuf + 4128768;
    bf16* w_ffn2   = wbuf + 5177344;

    dim3 blk(256);
    constexpr int NOFLIP = 1 << 30;

    WSrcs srcs;
    srcs.p[0] = d_in[I_fm + 0]; srcs.p[1] = d_in[I_bm + 0];
    srcs.p[2] = d_in[I_fm + 3]; srcs.p[3] = d_in[I_bm + 3];
    srcs.p[4] = d_in[I_fm + 4]; srcs.p[5] = d_in[I_bm + 4];
    srcs.p[6] = d_in[I_fm + 8]; srcs.p[7] = d_in[I_bm + 8];
    srcs.p[8] = d_in[I_fusion_w]; srcs.p[9] = d_in[I_ccp_w];
    srcs.p[10] = d_in[I_ffn_w1]; srcs.p[11] = d_in[I_ffn_w2];

    // fused setup: weight conversion + anT + center norms + dtype flag + input LN
    setup_kernel<<<dim3(512, 17), blk, 0, stream>>>(
        srcs, wbuf, d_in[I_fm + 6], d_in[I_bm + 6], centers, anT, cn, flg,
        X, n1g, n1b, xn);

    // in_proj both dirs + ccp projection merged: N = 4096 (split xp/zb) + 512 (projb)
    mfma_gemm<128, 64, 2, 2><<<dim3(72, 16, 1), blk, 0, stream>>>(
        xn, kD, 0, w_in, kD, 0, nullptr, 0, nullptr, xp, nullptr, 2048, 0, NOFLIP, 0, flg, zb,
        w_ccp, ccp_b, projb, 4096);

    // conv both dirs
    conv_kernel<<<2 * kM * kDI / 256, blk, 0, stream>>>(
        xp, d_in[I_fm + 1], d_in[I_fm + 2], d_in[I_bm + 1], d_in[I_bm + 2], xc, flg);

    // fused xproj + delta (one block per row; xp dead -> deltaH aliases it)
    xproj_delta_kernel<<<kM, blk, 0, stream>>>(
        xc, w_xp, w_dt, d_in[I_fm + 5], d_in[I_bm + 5], xdbl, deltaH, flg);

    // fused local scan (single sequential pass) + chunk combine + parallel correction
    scan_phase1<<<2048, blk, 0, stream>>>(xc, xdbl, deltaH, anT, PA, HLh, ymul, flg);
    scan_phase2<<<256, blk, 0, stream>>>(PA, HLh);
    scan_fix<<<16384, blk, 0, stream>>>(xc, xdbl, zb, deltaH, anT,
                                        d_in[I_fm + 7], d_in[I_bm + 7], PA, ymul, flg);

    // out_proj both dirs: z-batched; z=1 (bm) rows flipped back; 32x64 tiles -> 1024 blocks
    mfma_gemm<32, 64, 1, 4><<<dim3(8, 64, 2), blk, 0, stream>>>(
        ymul, 2 * kDI, kDI, w_out, kDI, 524288, nullptr, 0, nullptr, fb, nullptr, 2 * kD, kD,
        NOFLIP, 1, flg, nullptr, nullptr, nullptr, nullptr, NOFLIP);

    // mamba_out = fb @ fusion_w^T + fusion_b  (32x64 tiles -> 512 blocks)
    mfma_gemm<32, 64, 1, 4><<<dim3(8, 64, 1), blk, 0, stream>>>(
        fb, 2 * kD, 0, w_fusion, 2 * kD, 0, fusion_b, 0, nullptr, mo, nullptr, kD, 0,
        NOFLIP, 0, flg, nullptr, nullptr, nullptr, nullptr, NOFLIP);

    // fused cc + gate + residual + FFN-LN
    post_kernel<<<kM, blk, 0, stream>>>(projb, centers, cn, xn, cc_alpha, ccn_g, ccn_b,
                                        X, mo, gate_w, gate_b, ffn_g, ffn_b, xmid, hln, flg);

    // FFN
    mfma_gemm<64, 64, 2, 2><<<dim3(32, 32, 1), blk, 0, stream>>>(
        hln, kD, 0, w_ffn1, kD, 0, ffn_b1, 2, nullptr, ffnh, nullptr, 4 * kD, 0, NOFLIP, 0, flg,
        nullptr, nullptr, nullptr, nullptr, NOFLIP);
    mfma_gemm<32, 64, 1, 4><<<dim3(8, 64, 1), blk, 0, stream>>>(
        ffnh, 4 * kD, 0, w_ffn2, 4 * kD, 0, ffn_b2, 0, xmid, nullptr, d_out, kD, 0,
        NOFLIP, 0, flg, nullptr, nullptr, nullptr, nullptr, NOFLIP);
}

// Round 13
// 368.839 us; speedup vs baseline: 1.2191x; 1.2191x over previous
//
#include <hip/hip_runtime.h>
#include <hip/hip_bf16.h>
#include <hip/hip_fp16.h>
#include <math.h>

using bf16 = __hip_bfloat16;

typedef __attribute__((ext_vector_type(8))) short v8s;   // 8 bf16 = 4 VGPRs
typedef __attribute__((ext_vector_type(4))) short v4s;   // 4 bf16 = 2 VGPRs
typedef __attribute__((ext_vector_type(4))) float v4f;   // MFMA accumulator

// Problem constants
constexpr int kB   = 2;
constexpr int kL   = 1024;
constexpr int kD   = 512;    // d_model
constexpr int kDI  = 1024;   // inner dim
constexpr int kNS  = 16;     // d_state
constexpr int kDTR = 32;     // dt_rank
constexpr int kKC  = 4;      // conv width
constexpr int kNC  = 8;      // clusters
constexpr int kM   = kB * kL;  // 2048 rows
constexpr int kCH  = 32;       // scan chunks
constexpr int kCL  = kL / kCH; // 32 steps per chunk
constexpr float kEPS = 1e-5f;

static __device__ __forceinline__ float toF(bf16 x) { return __bfloat162float(x); }
static __device__ __forceinline__ float b2f(short u) {
    unsigned int x = ((unsigned int)(unsigned short)u) << 16;
    return __uint_as_float(x);
}

// flag-dispatched raw-input load: flag=1 -> fp32, flag=0 -> bf16
static __device__ __forceinline__ float ldin(const void* p, int i, int f32) {
    if (f32) return ((const float*)p)[i];
    return toF(((const bf16*)p)[i]);
}

static __device__ __forceinline__ int flipL(int r) { return r ^ (kL - 1); }

// ---------------- block reduce (256 threads = 4 waves) ----------------
static __device__ __forceinline__ float blockReduceSum(float v, float* s) {
    __syncthreads();
#pragma unroll
    for (int o = 32; o > 0; o >>= 1) v += __shfl_down(v, o, 64);
    int lane = threadIdx.x & 63, wid = threadIdx.x >> 6;
    if (lane == 0) s[wid] = v;
    __syncthreads();
    if (threadIdx.x == 0) {
        float t = 0.f;
        for (int i = 0; i < 4; ++i) t += s[i];
        s[4] = t;
    }
    __syncthreads();
    return s[4];
}

// per-block dtype probe: 0 = bf16, 1 = f32 (all threads get result)
static __device__ __forceinline__ int detect_local(const unsigned short* x, float* sred) {
    float c = 0.f;
    for (int i = threadIdx.x; i < 512; i += 256) {
        unsigned short h = x[2 * i];  // even (low) halves
        int e = (h >> 7) & 0xFF;
        if (e >= 100 && e <= 140) c += 1.f;
    }
    float tot = blockReduceSum(c, sred);
    return (tot >= 256.f) ? 0 : 1;
}

// ---------------- fused setup: weight conversion + anT + cnorm + flag + input LN ----------------
// grid (512, 17). y<12: wconv tile y. y==12: x<128 anT; x in [128,136) cnorm; x==136 flag.
// y in 13..16: LayerNorm of input row (y-13)*512 + x -> xn.
struct WSrcs { const void* p[12]; };

__global__ __launch_bounds__(256) void setup_kernel(WSrcs s, bf16* __restrict__ dst,
                                                    const void* __restrict__ alog_f,
                                                    const void* __restrict__ alog_b,
                                                    const void* __restrict__ centers,
                                                    float* __restrict__ anT,
                                                    float* __restrict__ cn,
                                                    int* __restrict__ flag,
                                                    const void* __restrict__ X,
                                                    const void* __restrict__ n1g,
                                                    const void* __restrict__ n1b,
                                                    bf16* __restrict__ xn) {
    __shared__ float sred[8];
    int f32 = detect_local((const unsigned short*)X, sred);
    int t = blockIdx.y;
    if (t < 12) {
        const int sz[12]  = {1048576, 1048576, 65536, 65536, 32768, 32768,
                             524288, 524288, 524288, 262144, 1048576, 1048576};
        const int off[12] = {0, 1048576, 2097152, 2162688, 2228224, 2260992,
                             2293760, 2818048, 3342336, 3866624, 4128768, 5177344};
        int n = sz[t];
        const void* src = s.p[t];
        bf16* d = dst + off[t];
        for (int i = blockIdx.x * 256 + threadIdx.x; i < n; i += 512 * 256)
            d[i] = __float2bfloat16(ldin(src, i, f32));
    } else if (t == 12) {
        int bx = blockIdx.x;
        if (bx < 128) {
            int tid = bx * 256 + threadIdx.x;  // 32768
            int d = tid & (kDI - 1);
            int n = (tid >> 10) & (kNS - 1);
            int dir = tid >> 14;
            anT[tid] = -__expf(ldin(dir ? alog_b : alog_f, d * kNS + n, f32));
        } else if (bx < 136) {
            int c = bx - 128;
            float ssum = 0.f;
            for (int i = threadIdx.x; i < kD; i += 256) {
                float v = ldin(centers, c * kD + i, f32);
                ssum += v * v;
            }
            float tot = blockReduceSum(ssum, sred);
            if (threadIdx.x == 0) cn[c] = sqrtf(tot);
        } else if (bx == 136) {
            if (threadIdx.x == 0) *flag = f32;
        }
    } else {
        // input LayerNorm, one block per row
        int row = (t - 13) * 512 + blockIdx.x;
        int i = threadIdx.x;
        size_t base = (size_t)row * kD;
        float x0 = ldin(X, base + i, f32), x1 = ldin(X, base + i + 256, f32);
        float mean = blockReduceSum(x0 + x1, sred) * (1.f / kD);
        float vs = blockReduceSum(x0 * x0 + x1 * x1, sred) * (1.f / kD) - mean * mean;
        float rstd = rsqrtf(vs + kEPS);
        xn[base + i]       = __float2bfloat16((x0 - mean) * rstd * ldin(n1g, i, f32)       + ldin(n1b, i, f32));
        xn[base + i + 256] = __float2bfloat16((x1 - mean) * rstd * ldin(n1g, i + 256, f32) + ldin(n1b, i + 256, f32));
    }
}

// ---------------- MFMA bf16 GEMM with z-batch + global_load_lds + XOR-swizzled LDS ----------------
template <int BM, int BN, int WRN, int WCN>
__global__ __launch_bounds__(256) void mfma_gemm(const bf16* __restrict__ A, int lda, int aZOff,
                                                 const bf16* __restrict__ W, int K, int wZOff,
                                                 const void* __restrict__ bias, int act,
                                                 const float* __restrict__ resid,
                                                 bf16* __restrict__ outB,
                                                 void* __restrict__ outRaw,
                                                 int ldo, int oZOff,
                                                 int flipN0, int zflip,
                                                 const int* __restrict__ flg,
                                                 bf16* __restrict__ outSplitZ,
                                                 const bf16* __restrict__ wCcp,
                                                 const void* __restrict__ ccpBias,
                                                 bf16* __restrict__ outCcp,
                                                 int nSplit2) {
    __shared__ bf16 As[BM * 64];
    __shared__ bf16 Bs[BN * 64];
    constexpr int FR = BM / WRN / 16;
    constexpr int FC = BN / WCN / 16;
    constexpr int AV = BM / 32;  // 16B chunks per thread for A tile
    constexpr int BV = BN / 32;

    int f32 = *flg;
    int tid = threadIdx.x;
    int z = blockIdx.z;
    const bf16* Ab = A + (size_t)z * aZOff;
    int m0 = blockIdx.y * BM, n0 = blockIdx.x * BN;
    const bf16* Wb = W + (size_t)z * wZOff;
    int nrow0 = n0;
    bool isCcp = (wCcp != nullptr) && (n0 >= nSplit2);
    if (isCcp) { Wb = wCcp; nrow0 = n0 - nSplit2; }
    int lane = tid & 63, w = tid >> 6;
    int wr = w % WRN, wc = w / WRN;
    int rbase = wr * (BM / WRN), cbase = wc * (BN / WCN);
    int quad = lane >> 4, lrow = lane & 15;
    int wbase = tid & ~63;  // wave-uniform

    v4f acc[FR][FC];
#pragma unroll
    for (int i = 0; i < FR; ++i)
#pragma unroll
        for (int j = 0; j < FC; ++j)
#pragma unroll
            for (int r = 0; r < 4; ++r) acc[i][j][r] = 0.f;

    for (int kt = 0; kt < K; kt += 64) {
#pragma unroll
        for (int i = 0; i < AV; ++i) {
            int v = i * 256 + tid;
            int row = v >> 3;
            int c8 = ((v & 7) * 8) ^ ((row & 7) * 8);  // swizzled source chunk
            const bf16* gp = Ab + (size_t)(m0 + row) * lda + kt + c8;
            __builtin_amdgcn_global_load_lds(
                (const __attribute__((address_space(1))) void*)gp,
                (__attribute__((address_space(3))) void*)&As[(i * 256 + wbase) * 8],
                16, 0, 0);
        }
#pragma unroll
        for (int i = 0; i < BV; ++i) {
            int v = i * 256 + tid;
            int row = v >> 3;
            int c8 = ((v & 7) * 8) ^ ((row & 7) * 8);
            const bf16* gp = Wb + (size_t)(nrow0 + row) * K + kt + c8;
            __builtin_amdgcn_global_load_lds(
                (const __attribute__((address_space(1))) void*)gp,
                (__attribute__((address_space(3))) void*)&Bs[(i * 256 + wbase) * 8],
                16, 0, 0);
        }
        __syncthreads();
#pragma unroll
        for (int k0 = 0; k0 < 64; k0 += 32) {
            v8s a[FR], b[FC];
#pragma unroll
            for (int fr = 0; fr < FR; ++fr) {
                int r = rbase + fr * 16 + lrow;
                a[fr] = *reinterpret_cast<const v8s*>(
                    &As[r * 64 + ((k0 + quad * 8) ^ ((r & 7) * 8))]);
            }
#pragma unroll
            for (int fc = 0; fc < FC; ++fc) {
                int r = cbase + fc * 16 + lrow;
                b[fc] = *reinterpret_cast<const v8s*>(
                    &Bs[r * 64 + ((k0 + quad * 8) ^ ((r & 7) * 8))]);
            }
#pragma unroll
            for (int fr = 0; fr < FR; ++fr)
#pragma unroll
                for (int fc = 0; fc < FC; ++fc)
                    acc[fr][fc] = __builtin_amdgcn_mfma_f32_16x16x32_bf16(a[fr], b[fc], acc[fr][fc], 0, 0, 0);
        }
        __syncthreads();
    }

    // epilogue: C/D layout col=lane&15, row=quad*4+reg  [m89-verified]
    bf16* outBz = outB ? outB + (size_t)z * oZOff : nullptr;
#pragma unroll
    for (int fr = 0; fr < FR; ++fr) {
#pragma unroll
        for (int fc = 0; fc < FC; ++fc) {
            int ncol = n0 + cbase + fc * 16 + lrow;
            float bi = bias ? ldin(bias, ncol, f32) : 0.f;
            bool doflip = (ncol >= flipN0) || (zflip && z == 1);
#pragma unroll
            for (int r = 0; r < 4; ++r) {
                int m = m0 + rbase + fr * 16 + quad * 4 + r;
                float vv = acc[fr][fc][r] + bi;
                if (act == 2) vv = 0.5f * vv * (1.f + erff(vv * 0.70710678118654752440f));
                if (resid) vv += resid[(size_t)m * ldo + ncol];
                if (outCcp && ncol >= nSplit2) {
                    float v2 = vv + ldin(ccpBias, ncol - nSplit2, f32);
                    outCcp[(size_t)m * kD + (ncol - nSplit2)] = __float2bfloat16(v2);
                } else if (outSplitZ) {
                    int dir = (ncol >> 11) & 1;
                    int isz = (ncol >> 10) & 1;
                    int c2 = dir * 1024 + (ncol & 1023);
                    int mo_ = dir ? flipL(m) : m;
                    bf16* dst = isz ? outSplitZ : outB;
                    dst[(size_t)mo_ * 2048 + c2] = __float2bfloat16(vv);
                } else {
                    int mo_ = doflip ? flipL(m) : m;
                    size_t oi = (size_t)mo_ * ldo + ncol;
                    if (outBz) outBz[oi] = __float2bfloat16(vv);
                    else if (f32) ((float*)outRaw)[oi] = vv;
                    else ((bf16*)outRaw)[oi] = __float2bfloat16(vv);
                }
            }
        }
    }
}

// ---------------- depthwise causal conv + silu, both dirs ----------------
__global__ __launch_bounds__(256) void conv_kernel(const bf16* __restrict__ xp,
                                                   const void* __restrict__ cw_f,
                                                   const void* __restrict__ cb_f,
                                                   const void* __restrict__ cw_b,
                                                   const void* __restrict__ cb_b,
                                                   bf16* __restrict__ xc,
                                                   const int* __restrict__ flg) {
    int f32 = *flg;
    int tid = blockIdx.x * 256 + threadIdx.x;  // 2*kM*kDI
    int d = tid & (kDI - 1);
    int r = (tid >> 10) & (kM - 1);
    int dir = tid >> 21;
    int l = r & (kL - 1);
    int b = r >> 10;
    const void* cw = dir ? cw_b : cw_f;
    const void* cb = dir ? cb_b : cb_f;
    float acc = ldin(cb, d, f32);
#pragma unroll
    for (int k = 0; k < kKC; ++k) {
        int ll = l - (kKC - 1) + k;
        if (ll >= 0)
            acc += ldin(cw, d * kKC + k, f32) *
                   toF(xp[(size_t)(b * kL + ll) * (2 * kDI) + dir * kDI + d]);
    }
    float s = acc / (1.f + __expf(-acc));
    xc[(size_t)r * (2 * kDI) + dir * kDI + d] = __float2bfloat16(s);
}

// ---------------- delta precompute: dl = softplus(dt @ wdt^T + dtb) ----------------
// xdbl: (2048 x 128) = [dt_f(32)|B_f(16)|C_f(16) | dt_b|B_b|C_b]
__global__ __launch_bounds__(256) void delta_kernel(const bf16* __restrict__ xdbl,
                                                    const bf16* __restrict__ wdt,
                                                    const void* __restrict__ dtb_f,
                                                    const void* __restrict__ dtb_b,
                                                    __half* __restrict__ deltaH,
                                                    const int* __restrict__ flg) {
    __shared__ float arow[kDTR];
    int f32 = *flg;
    int m = blockIdx.y;    // b*L + l
    int dir = blockIdx.z;
    int d = blockIdx.x * 256 + threadIdx.x;
    if (threadIdx.x < kDTR)
        arow[threadIdx.x] = toF(xdbl[(size_t)m * 128 + dir * 64 + threadIdx.x]);
    __syncthreads();
    float acc = ldin(dir ? dtb_b : dtb_f, d, f32);
    const v8s* wv = reinterpret_cast<const v8s*>(wdt + ((size_t)dir * kDI + d) * kDTR);
#pragma unroll
    for (int t = 0; t < 4; ++t) {
        v8s w8 = wv[t];
#pragma unroll
        for (int k = 0; k < 8; ++k) acc += arow[t * 8 + k] * b2f(w8[k]);
    }
    acc = (acc > 20.f) ? acc : log1pf(__expf(acc));
    deltaH[((size_t)dir * kM + m) * kDI + d] = __float2half(acc);
}

// ---------------- fused local scan: y_local + chunk summaries + cumsum(dl) ----------------
// tid bits: [1:0]=n4, [11:2]=d, [16:12]=c, [17]=b, [18]=dir  (524288 threads)
// PA/HLh layout is d-innermost: [((g*kCH + c)*kNS + n)*kDI + d], g = dir*2+b.
__global__ __launch_bounds__(256) void scan_phase1(const bf16* __restrict__ xc,
                                                   const bf16* __restrict__ xdbl,
                                                   __half* __restrict__ deltaS,
                                                   const float* __restrict__ anT,
                                                   float* __restrict__ PA,
                                                   __half* __restrict__ HLh,
                                                   bf16* __restrict__ ymul,
                                                   const int* __restrict__ flg) {
    int tid = blockIdx.x * 256 + threadIdx.x;
    int n4  = tid & 3;
    int d   = (tid >> 2) & (kDI - 1);
    int c   = (tid >> 12) & (kCH - 1);
    int b   = (tid >> 17) & 1;
    int dir = tid >> 18;
    float an[4], h[4], pa[4];
#pragma unroll
    for (int j = 0; j < 4; ++j) {
        an[j] = anT[((size_t)dir * kNS + n4 * 4 + j) * kDI + d];
        h[j] = 0.f;
        pa[j] = 1.f;
    }
    __half* dptr = deltaS + ((size_t)dir * kM + (size_t)b * kL) * kDI + d;
    float s = 0.f;
    int l0 = c * kCL;
    for (int l = l0; l < l0 + kCL; ++l) {
        size_t rb = (size_t)b * kL + l;
        float dl = __half2float(dptr[(size_t)l * kDI]);
        s += dl;
        float xcv = toF(xc[rb * (2 * kDI) + dir * kDI + d]);
        float du = dl * xcv;
        v4s Bv = *reinterpret_cast<const v4s*>(xdbl + rb * 128 + dir * 64 + kDTR + n4 * 4);
        v4s Cv = *reinterpret_cast<const v4s*>(xdbl + rb * 128 + dir * 64 + kDTR + kNS + n4 * 4);
        float yp = 0.f;
#pragma unroll
        for (int j = 0; j < 4; ++j) {
            float a = __expf(dl * an[j]);
            pa[j] *= a;
            h[j] = a * h[j] + du * b2f(Bv[j]);
            yp += h[j] * b2f(Cv[j]);
        }
        yp += __shfl_xor(yp, 1);
        yp += __shfl_xor(yp, 2);
        if (n4 == 0) {
            ymul[rb * (2 * kDI) + dir * kDI + d] = __float2bfloat16(yp);
            dptr[(size_t)l * kDI] = __float2half(s);  // in-place: all lanes read dl above first
        }
    }
    int g = dir * kB + b;
    size_t o = (((size_t)g * kCH + c) * kNS + n4 * 4) * kDI + d;
#pragma unroll
    for (int j = 0; j < 4; ++j) {
        PA[o + (size_t)j * kDI] = pa[j];
        HLh[o + (size_t)j * kDI] = __float2half(h[j]);
    }
}

// combine over chunks; write HIN (incoming state per chunk) in-place into PA
// tid bits: [9:0]=d, [13:10]=n, [15:14]=g  (65536 threads) — d-innermost -> coalesced
__global__ __launch_bounds__(256) void scan_phase2(float* __restrict__ PA,
                                                   const __half* __restrict__ HLh) {
    int tid = blockIdx.x * 256 + threadIdx.x;
    int d = tid & (kDI - 1);
    int n = (tid >> 10) & (kNS - 1);
    int g = tid >> 14;
    float h = 0.f;
    for (int c = 0; c < kCH; ++c) {
        size_t idx = (((size_t)g * kCH + c) * kNS + n) * kDI + d;
        float pav = PA[idx];
        float hlv = __half2float(HLh[idx]);
        PA[idx] = h;  // HIN for chunk c
        h = pav * h + hlv;
    }
}

// ---------------- parallel correction: y = y_local + C.(exp(an*s) * h_in) + xc*D, gate silu(z) ----------------
// tid bits: [9:0]=d, [19:10]=l, [20]=b, [21]=dir  (4,194,304 threads)
__global__ __launch_bounds__(256) void scan_fix(const bf16* __restrict__ xc,
                                                const bf16* __restrict__ xdbl,
                                                const bf16* __restrict__ zb,
                                                const __half* __restrict__ sbuf,
                                                const float* __restrict__ anT,
                                                const void* __restrict__ dp_f,
                                                const void* __restrict__ dp_b,
                                                const float* __restrict__ HIN,
                                                bf16* __restrict__ ymul,
                                                const int* __restrict__ flg) {
    int f32 = *flg;
    int tid = blockIdx.x * 256 + threadIdx.x;
    int d   = tid & (kDI - 1);
    int l   = (tid >> 10) & (kL - 1);
    int b   = (tid >> 20) & 1;
    int dir = tid >> 21;
    int c   = l / kCL;
    size_t rb = (size_t)b * kL + l;
    float s = __half2float(sbuf[((size_t)dir * kM + rb) * kDI + d]);
    int g = dir * kB + b;
    const float* hin = HIN + (((size_t)g * kCH + c) * kNS) * kDI + d;
    const float* anp = anT + (size_t)dir * kNS * kDI + d;
    const bf16* Cp = xdbl + rb * 128 + dir * 64 + kDTR + kNS;
    float ycorr = 0.f;
#pragma unroll
    for (int n = 0; n < kNS; ++n) {
        float an = anp[(size_t)n * kDI];
        ycorr += toF(Cp[n]) * __expf(an * s) * hin[(size_t)n * kDI];
    }
    size_t yi = rb * (2 * kDI) + dir * kDI + d;
    float xcv = toF(xc[yi]);
    float Dv = ldin(dir ? dp_b : dp_f, d, f32);
    float y = toF(ymul[yi]) + ycorr + xcv * Dv;
    float zv = toF(zb[yi]);
    float sz = zv / (1.f + __expf(-zv));
    ymul[yi] = __float2bfloat16(y * sz);
}

// ---------------- fused context-cluster + gate + residual + FFN-LN ----------------
__global__ __launch_bounds__(256) void post_kernel(const bf16* __restrict__ proj,
                                                   const void* __restrict__ centers,
                                                   const float* __restrict__ cn,
                                                   const bf16* __restrict__ xn,
                                                   const void* __restrict__ alpha_p,
                                                   const void* __restrict__ ccg,
                                                   const void* __restrict__ ccb,
                                                   const void* __restrict__ X,
                                                   const bf16* __restrict__ mo,
                                                   const void* __restrict__ gw,
                                                   const void* __restrict__ gb,
                                                   const void* __restrict__ fg,
                                                   const void* __restrict__ fbb,
                                                   float* __restrict__ xmid,
                                                   bf16* __restrict__ hln,
                                                   const int* __restrict__ flg) {
    __shared__ float sred[8];
    __shared__ float sims[kNC];
    int f32 = *flg;
    int row = blockIdx.x;
    int i = threadIdx.x;
    size_t base = (size_t)row * kD;
    float p0 = toF(proj[base + i]), p1 = toF(proj[base + i + 256]);
    float sumsq = blockReduceSum(p0 * p0 + p1 * p1, sred);
    float pn = fmaxf(sqrtf(sumsq), 1e-12f);
    for (int c = 0; c < kNC; ++c) {
        float part = p0 * ldin(centers, c * kD + i, f32) + p1 * ldin(centers, c * kD + i + 256, f32);
        float dot = blockReduceSum(part, sred);
        if (threadIdx.x == 0) sims[c] = dot / (pn * fmaxf(cn[c], 1e-12f));
    }
    __syncthreads();
    float mx = -1e30f;
#pragma unroll
    for (int c = 0; c < kNC; ++c) mx = fmaxf(mx, sims[c]);
    float wv[kNC], se = 0.f;
#pragma unroll
    for (int c = 0; c < kNC; ++c) { wv[c] = __expf(sims[c] - mx); se += wv[c]; }
    float inv = 1.f / se;
    float ctx0 = 0.f, ctx1 = 0.f;
#pragma unroll
    for (int c = 0; c < kNC; ++c) {
        float wc = wv[c] * inv;
        ctx0 += wc * ldin(centers, c * kD + i, f32);
        ctx1 += wc * ldin(centers, c * kD + i + 256, f32);
    }
    float alpha = ldin(alpha_p, 0, f32);
    float x0 = toF(xn[base + i]), x1 = toF(xn[base + i + 256]);
    float t0 = x0 + alpha * ctx0;
    float t1 = x1 + alpha * ctx1;
    float mean = blockReduceSum(t0 + t1, sred) * (1.f / kD);
    float vs = blockReduceSum(t0 * t0 + t1 * t1, sred) * (1.f / kD) - mean * mean;
    float rstd = rsqrtf(vs + kEPS);
    float cc0 = (t0 - mean) * rstd * ldin(ccg, i, f32)       + ldin(ccb, i, f32);
    float cc1 = (t1 - mean) * rstd * ldin(ccg, i + 256, f32) + ldin(ccb, i + 256, f32);
    // gate
    float d0 = blockReduceSum(x0 * ldin(gw, i, f32) + x1 * ldin(gw, i + 256, f32), sred);
    float d1 = blockReduceSum(x0 * ldin(gw, kD + i, f32) + x1 * ldin(gw, kD + i + 256, f32), sred);
    d0 += ldin(gb, 0, f32);
    d1 += ldin(gb, 1, f32);
    float gmx = fmaxf(d0, d1);
    float e0 = __expf(d0 - gmx), e1 = __expf(d1 - gmx);
    float gs = e0 + e1;
    float g0 = e0 / gs, g1 = e1 / gs;
    float xm0 = ldin(X, base + i, f32)       + g0 * toF(mo[base + i])       + g1 * cc0;
    float xm1 = ldin(X, base + i + 256, f32) + g0 * toF(mo[base + i + 256]) + g1 * cc1;
    xmid[base + i] = xm0;
    xmid[base + i + 256] = xm1;
    // FFN LayerNorm
    float mean2 = blockReduceSum(xm0 + xm1, sred) * (1.f / kD);
    float vs2 = blockReduceSum(xm0 * xm0 + xm1 * xm1, sred) * (1.f / kD) - mean2 * mean2;
    float rstd2 = rsqrtf(vs2 + kEPS);
    hln[base + i]       = __float2bfloat16((xm0 - mean2) * rstd2 * ldin(fg, i, f32)       + ldin(fbb, i, f32));
    hln[base + i + 256] = __float2bfloat16((xm1 - mean2) * rstd2 * ldin(fg, i + 256, f32) + ldin(fbb, i + 256, f32));
}

// ---------------- launch ----------------
extern "C" void kernel_launch(void* const* d_in, const int* in_sizes, int n_in,
                              void* d_out, int out_size, void* d_ws, size_t ws_size,
                              hipStream_t stream) {
    bool sig = (n_in > 3 && in_sizes[3] == 2 * kDI * kD);
    int I_fusion_w = sig ? 21 : 3,  I_fusion_b = sig ? 22 : 4;
    int I_centers  = sig ? 23 : 5,  I_ccp_w    = sig ? 24 : 6,  I_ccp_b = sig ? 25 : 7;
    int I_ccn_g    = sig ? 26 : 8,  I_ccn_b    = sig ? 27 : 9,  I_alpha = sig ? 28 : 10;
    int I_gate_w   = sig ? 29 : 11, I_gate_b   = sig ? 30 : 12;
    int I_ffn_g    = sig ? 31 : 13, I_ffn_b    = sig ? 32 : 14;
    int I_ffn_w1   = sig ? 33 : 15, I_ffn_b1   = sig ? 34 : 16;
    int I_ffn_w2   = sig ? 35 : 17, I_ffn_b2   = sig ? 36 : 18;
    int I_fm       = sig ? 3  : 19, I_bm       = sig ? 12 : 28;

    const void* X        = d_in[0];
    const void* n1g      = d_in[1];
    const void* n1b      = d_in[2];
    const void* fusion_b = d_in[I_fusion_b];
    const void* centers  = d_in[I_centers];
    const void* ccp_b    = d_in[I_ccp_b];
    const void* ccn_g    = d_in[I_ccn_g];
    const void* ccn_b    = d_in[I_ccn_b];
    const void* cc_alpha = d_in[I_alpha];
    const void* gate_w   = d_in[I_gate_w];
    const void* gate_b   = d_in[I_gate_b];
    const void* ffn_g    = d_in[I_ffn_g];
    const void* ffn_b    = d_in[I_ffn_b];
    const void* ffn_b1   = d_in[I_ffn_b1];
    const void* ffn_b2   = d_in[I_ffn_b2];

    // ---- workspace layout (float units) — total ~63.4 MB ----
    float* ws = (float*)d_ws;
    int* flg  = (int*)d_ws;           // ws[0]
    float* cn = ws + 8;               // 8 floats
    float*  anT  = ws + 32;                          // 32,768 f  (2 x 16 x 1024)
    float*  PA   = anT + 32768;                      // 2,097,152 f (d-innermost chunk summaries -> HIN)
    __half* HLh  = (__half*)(PA + 2097152);          // 2,097,152 half = 1,048,576 f
    bf16*  xn   = (bf16*)((float*)HLh + 1048576);    // 2048x512 bf16   = 524,288 f
    bf16*  xp   = (bf16*)((float*)xn + 524288);      // 2048x2048 bf16  = 2,097,152 f
    bf16*  zb   = (bf16*)((float*)xp + 2097152);     // 2048x2048 bf16  = 2,097,152 f
    bf16*  xc   = (bf16*)((float*)zb + 2097152);     // 2048x2048 bf16  = 2,097,152 f
    bf16*  xdbl = (bf16*)((float*)xc + 2097152);     // 2048x128 bf16   = 131,072 f
    bf16*  ymul = (bf16*)((float*)xdbl + 131072);    // 2048x2048 bf16  = 2,097,152 f
    bf16*  wbuf = (bf16*)((float*)ymul + 2097152);   // 6,225,920 bf16  = 3,112,960 f
    bf16*  projb = (bf16*)((float*)wbuf + 3112960);  // 2048x512 bf16   = 524,288 f (dedicated)
    // aliases of dead regions (size-checked):
    __half* deltaH = (__half*)xp;    // 4,194,304 half exact (xp dead after conv); becomes s(l) after phase1
    bf16*  fb    = (bf16*)HLh;       // 2,097,152 bf16 exact (HLh dead after phase2; out_proj writes later)
    bf16*  mo    = (bf16*)PA;        // 524,288 f <= PA (HIN dead after scan_fix; fusion writes later)
    float* xmid  = PA + 524288;      // 1,048,576 f, disjoint from mo, within PA region (2M)
    bf16*  hln   = xc;               // after scan_fix
    bf16*  ffnh  = zb;               // after scan_fix (2M f exact)

    // weight views (order: fm_in, bm_in, fm_xproj, bm_xproj, fm_dt, bm_dt, fm_out, bm_out, fusion, ccp, ffn1, ffn2)
    bf16* w_in     = wbuf + 0;        // [fm|bm] concat, N=4096 x K=512
    bf16* w_xp     = wbuf + 2097152;  // 2 x (64 x 1024)
    bf16* w_dt     = wbuf + 2228224;  // 2 x (1024 x 32)
    bf16* w_out    = wbuf + 2293760;  // 2 x (512 x 1024)
    bf16* w_fusion = wbuf + 3342336;
    bf16* w_ccp    = wbuf + 3866624;
    bf16* w_ffn1   = wbuf + 4128768;
    bf16* w_ffn2   = wbuf + 5177344;

    dim3 blk(256);
    constexpr int NOFLIP = 1 << 30;

    WSrcs srcs;
    srcs.p[0] = d_in[I_fm + 0]; srcs.p[1] = d_in[I_bm + 0];
    srcs.p[2] = d_in[I_fm + 3]; srcs.p[3] = d_in[I_bm + 3];
    srcs.p[4] = d_in[I_fm + 4]; srcs.p[5] = d_in[I_bm + 4];
    srcs.p[6] = d_in[I_fm + 8]; srcs.p[7] = d_in[I_bm + 8];
    srcs.p[8] = d_in[I_fusion_w]; srcs.p[9] = d_in[I_ccp_w];
    srcs.p[10] = d_in[I_ffn_w1]; srcs.p[11] = d_in[I_ffn_w2];

    // fused setup: weight conversion + anT + center norms + dtype flag + input LN
    setup_kernel<<<dim3(512, 17), blk, 0, stream>>>(
        srcs, wbuf, d_in[I_fm + 6], d_in[I_bm + 6], centers, anT, cn, flg,
        X, n1g, n1b, xn);

    // in_proj both dirs + ccp projection merged: N = 4096 (split xp/zb) + 512 (projb)
    mfma_gemm<128, 64, 2, 2><<<dim3(72, 16, 1), blk, 0, stream>>>(
        xn, kD, 0, w_in, kD, 0, nullptr, 0, nullptr, xp, nullptr, 2048, 0, NOFLIP, 0, flg, zb,
        w_ccp, ccp_b, projb, 4096);

    // conv both dirs
    conv_kernel<<<2 * kM * kDI / 256, blk, 0, stream>>>(
        xp, d_in[I_fm + 1], d_in[I_fm + 2], d_in[I_bm + 1], d_in[I_bm + 2], xc, flg);

    // xproj both dirs: z-batched MFMA (N=64, K=1024), 32x64 tiles
    mfma_gemm<32, 64, 1, 4><<<dim3(1, 64, 2), blk, 0, stream>>>(
        xc, 2 * kDI, kDI, w_xp, kDI, 65536, nullptr, 0, nullptr, xdbl, nullptr, 128, 64,
        NOFLIP, 0, flg, nullptr, nullptr, nullptr, nullptr, NOFLIP);

    // delta precompute (xp dead -> deltaH aliases it)
    delta_kernel<<<dim3(kDI / 256, kM, 2), blk, 0, stream>>>(
        xdbl, w_dt, d_in[I_fm + 5], d_in[I_bm + 5], deltaH, flg);

    // fused local scan (single sequential pass) + chunk combine + parallel correction
    scan_phase1<<<2048, blk, 0, stream>>>(xc, xdbl, deltaH, anT, PA, HLh, ymul, flg);
    scan_phase2<<<256, blk, 0, stream>>>(PA, HLh);
    scan_fix<<<16384, blk, 0, stream>>>(xc, xdbl, zb, deltaH, anT,
                                        d_in[I_fm + 7], d_in[I_bm + 7], PA, ymul, flg);

    // out_proj both dirs: z-batched; z=1 (bm) rows flipped back; 32x64 tiles -> 1024 blocks
    mfma_gemm<32, 64, 1, 4><<<dim3(8, 64, 2), blk, 0, stream>>>(
        ymul, 2 * kDI, kDI, w_out, kDI, 524288, nullptr, 0, nullptr, fb, nullptr, 2 * kD, kD,
        NOFLIP, 1, flg, nullptr, nullptr, nullptr, nullptr, NOFLIP);

    // mamba_out = fb @ fusion_w^T + fusion_b  (32x64 tiles -> 512 blocks)
    mfma_gemm<32, 64, 1, 4><<<dim3(8, 64, 1), blk, 0, stream>>>(
        fb, 2 * kD, 0, w_fusion, 2 * kD, 0, fusion_b, 0, nullptr, mo, nullptr, kD, 0,
        NOFLIP, 0, flg, nullptr, nullptr, nullptr, nullptr, NOFLIP);

    // fused cc + gate + residual + FFN-LN
    post_kernel<<<kM, blk, 0, stream>>>(projb, centers, cn, xn, cc_alpha, ccn_g, ccn_b,
                                        X, mo, gate_w, gate_b, ffn_g, ffn_b, xmid, hln, flg);

    // FFN
    mfma_gemm<64, 64, 2, 2><<<dim3(32, 32, 1), blk, 0, stream>>>(
        hln, kD, 0, w_ffn1, kD, 0, ffn_b1, 2, nullptr, ffnh, nullptr, 4 * kD, 0, NOFLIP, 0, flg,
        nullptr, nullptr, nullptr, nullptr, NOFLIP);
    mfma_gemm<32, 64, 1, 4><<<dim3(8, 64, 1), blk, 0, stream>>>(
        ffnh, 4 * kD, 0, w_ffn2, 4 * kD, 0, ffn_b2, 0, xmid, nullptr, d_out, kD, 0,
        NOFLIP, 0, flg, nullptr, nullptr, nullptr, nullptr, NOFLIP);
}

// Round 14
// 362.785 us; speedup vs baseline: 1.2395x; 1.0167x over previous
//
#include <hip/hip_runtime.h>
#include <hip/hip_bf16.h>
#include <hip/hip_fp16.h>
#include <math.h>

using bf16 = __hip_bfloat16;

typedef __attribute__((ext_vector_type(8))) short v8s;   // 8 bf16 = 4 VGPRs
typedef __attribute__((ext_vector_type(4))) short v4s;   // 4 bf16 = 2 VGPRs
typedef __attribute__((ext_vector_type(4))) float v4f;   // MFMA accumulator

// Problem constants
constexpr int kB   = 2;
constexpr int kL   = 1024;
constexpr int kD   = 512;    // d_model
constexpr int kDI  = 1024;   // inner dim
constexpr int kNS  = 16;     // d_state
constexpr int kDTR = 32;     // dt_rank
constexpr int kKC  = 4;      // conv width
constexpr int kNC  = 8;      // clusters
constexpr int kM   = kB * kL;  // 2048 rows
constexpr int kCH  = 32;       // scan chunks
constexpr int kCL  = kL / kCH; // 32 steps per chunk
constexpr float kEPS = 1e-5f;

static __device__ __forceinline__ float toF(bf16 x) { return __bfloat162float(x); }
static __device__ __forceinline__ float b2f(short u) {
    unsigned int x = ((unsigned int)(unsigned short)u) << 16;
    return __uint_as_float(x);
}

// flag-dispatched raw-input load: flag=1 -> fp32, flag=0 -> bf16
static __device__ __forceinline__ float ldin(const void* p, int i, int f32) {
    if (f32) return ((const float*)p)[i];
    return toF(((const bf16*)p)[i]);
}

static __device__ __forceinline__ int flipL(int r) { return r ^ (kL - 1); }

// ---------------- block reduce (256 threads = 4 waves) ----------------
static __device__ __forceinline__ float blockReduceSum(float v, float* s) {
    __syncthreads();
#pragma unroll
    for (int o = 32; o > 0; o >>= 1) v += __shfl_down(v, o, 64);
    int lane = threadIdx.x & 63, wid = threadIdx.x >> 6;
    if (lane == 0) s[wid] = v;
    __syncthreads();
    if (threadIdx.x == 0) {
        float t = 0.f;
        for (int i = 0; i < 4; ++i) t += s[i];
        s[4] = t;
    }
    __syncthreads();
    return s[4];
}

// per-block dtype probe: 0 = bf16, 1 = f32 (all threads get result)
static __device__ __forceinline__ int detect_local(const unsigned short* x, float* sred) {
    float c = 0.f;
    for (int i = threadIdx.x; i < 512; i += 256) {
        unsigned short h = x[2 * i];  // even (low) halves
        int e = (h >> 7) & 0xFF;
        if (e >= 100 && e <= 140) c += 1.f;
    }
    float tot = blockReduceSum(c, sred);
    return (tot >= 256.f) ? 0 : 1;
}

// ---------------- fused setup: weight conversion + anT + cnorm + flag + input LN ----------------
// grid (512, 17). y<12: wconv tile y. y==12: x<128 anT; x in [128,136) cnorm; x==136 flag.
// y in 13..16: LayerNorm of input row (y-13)*512 + x -> xn.
struct WSrcs { const void* p[12]; };

__global__ __launch_bounds__(256) void setup_kernel(WSrcs s, bf16* __restrict__ dst,
                                                    const void* __restrict__ alog_f,
                                                    const void* __restrict__ alog_b,
                                                    const void* __restrict__ centers,
                                                    float* __restrict__ anT,
                                                    float* __restrict__ cn,
                                                    int* __restrict__ flag,
                                                    const void* __restrict__ X,
                                                    const void* __restrict__ n1g,
                                                    const void* __restrict__ n1b,
                                                    bf16* __restrict__ xn) {
    __shared__ float sred[8];
    int f32 = detect_local((const unsigned short*)X, sred);
    int t = blockIdx.y;
    if (t < 12) {
        const int sz[12]  = {1048576, 1048576, 65536, 65536, 32768, 32768,
                             524288, 524288, 524288, 262144, 1048576, 1048576};
        const int off[12] = {0, 1048576, 2097152, 2162688, 2228224, 2260992,
                             2293760, 2818048, 3342336, 3866624, 4128768, 5177344};
        int n = sz[t];
        const void* src = s.p[t];
        bf16* d = dst + off[t];
        for (int i = blockIdx.x * 256 + threadIdx.x; i < n; i += 512 * 256)
            d[i] = __float2bfloat16(ldin(src, i, f32));
    } else if (t == 12) {
        int bx = blockIdx.x;
        if (bx < 128) {
            int tid = bx * 256 + threadIdx.x;  // 32768
            int d = tid & (kDI - 1);
            int n = (tid >> 10) & (kNS - 1);
            int dir = tid >> 14;
            anT[tid] = -__expf(ldin(dir ? alog_b : alog_f, d * kNS + n, f32));
        } else if (bx < 136) {
            int c = bx - 128;
            float ssum = 0.f;
            for (int i = threadIdx.x; i < kD; i += 256) {
                float v = ldin(centers, c * kD + i, f32);
                ssum += v * v;
            }
            float tot = blockReduceSum(ssum, sred);
            if (threadIdx.x == 0) cn[c] = sqrtf(tot);
        } else if (bx == 136) {
            if (threadIdx.x == 0) *flag = f32;
        }
    } else {
        // input LayerNorm, one block per row
        int row = (t - 13) * 512 + blockIdx.x;
        int i = threadIdx.x;
        size_t base = (size_t)row * kD;
        float x0 = ldin(X, base + i, f32), x1 = ldin(X, base + i + 256, f32);
        float mean = blockReduceSum(x0 + x1, sred) * (1.f / kD);
        float vs = blockReduceSum(x0 * x0 + x1 * x1, sred) * (1.f / kD) - mean * mean;
        float rstd = rsqrtf(vs + kEPS);
        xn[base + i]       = __float2bfloat16((x0 - mean) * rstd * ldin(n1g, i, f32)       + ldin(n1b, i, f32));
        xn[base + i + 256] = __float2bfloat16((x1 - mean) * rstd * ldin(n1g, i + 256, f32) + ldin(n1b, i + 256, f32));
    }
}

// ---------------- MFMA bf16 GEMM with z-batch + global_load_lds + XOR-swizzled LDS ----------------
// gridSwap=1: blockIdx.x indexes M (fastest-varying -> consecutive blocks share weight tile).
template <int BM, int BN, int WRN, int WCN>
__global__ __launch_bounds__(256) void mfma_gemm(const bf16* __restrict__ A, int lda, int aZOff,
                                                 const bf16* __restrict__ W, int K, int wZOff,
                                                 const void* __restrict__ bias, int act,
                                                 const float* __restrict__ resid,
                                                 bf16* __restrict__ outB,
                                                 void* __restrict__ outRaw,
                                                 int ldo, int oZOff,
                                                 int flipN0, int zflip,
                                                 const int* __restrict__ flg,
                                                 bf16* __restrict__ outSplitZ,
                                                 const bf16* __restrict__ wCcp,
                                                 const void* __restrict__ ccpBias,
                                                 bf16* __restrict__ outCcp,
                                                 int nSplit2, int gridSwap) {
    __shared__ bf16 As[BM * 64];
    __shared__ bf16 Bs[BN * 64];
    constexpr int FR = BM / WRN / 16;
    constexpr int FC = BN / WCN / 16;
    constexpr int AV = BM / 32;  // 16B chunks per thread for A tile
    constexpr int BV = BN / 32;

    int f32 = *flg;
    int tid = threadIdx.x;
    int z = blockIdx.z;
    const bf16* Ab = A + (size_t)z * aZOff;
    int bn = gridSwap ? blockIdx.y : blockIdx.x;
    int bm = gridSwap ? blockIdx.x : blockIdx.y;
    int m0 = bm * BM, n0 = bn * BN;
    const bf16* Wb = W + (size_t)z * wZOff;
    int nrow0 = n0;
    bool isCcp = (wCcp != nullptr) && (n0 >= nSplit2);
    if (isCcp) { Wb = wCcp; nrow0 = n0 - nSplit2; }
    int lane = tid & 63, w = tid >> 6;
    int wr = w % WRN, wc = w / WRN;
    int rbase = wr * (BM / WRN), cbase = wc * (BN / WCN);
    int quad = lane >> 4, lrow = lane & 15;
    int wbase = tid & ~63;  // wave-uniform

    v4f acc[FR][FC];
#pragma unroll
    for (int i = 0; i < FR; ++i)
#pragma unroll
        for (int j = 0; j < FC; ++j)
#pragma unroll
            for (int r = 0; r < 4; ++r) acc[i][j][r] = 0.f;

    for (int kt = 0; kt < K; kt += 64) {
#pragma unroll
        for (int i = 0; i < AV; ++i) {
            int v = i * 256 + tid;
            int row = v >> 3;
            int c8 = ((v & 7) * 8) ^ ((row & 7) * 8);  // swizzled source chunk
            const bf16* gp = Ab + (size_t)(m0 + row) * lda + kt + c8;
            __builtin_amdgcn_global_load_lds(
                (const __attribute__((address_space(1))) void*)gp,
                (__attribute__((address_space(3))) void*)&As[(i * 256 + wbase) * 8],
                16, 0, 0);
        }
#pragma unroll
        for (int i = 0; i < BV; ++i) {
            int v = i * 256 + tid;
            int row = v >> 3;
            int c8 = ((v & 7) * 8) ^ ((row & 7) * 8);
            const bf16* gp = Wb + (size_t)(nrow0 + row) * K + kt + c8;
            __builtin_amdgcn_global_load_lds(
                (const __attribute__((address_space(1))) void*)gp,
                (__attribute__((address_space(3))) void*)&Bs[(i * 256 + wbase) * 8],
                16, 0, 0);
        }
        __syncthreads();
#pragma unroll
        for (int k0 = 0; k0 < 64; k0 += 32) {
            v8s a[FR], b[FC];
#pragma unroll
            for (int fr = 0; fr < FR; ++fr) {
                int r = rbase + fr * 16 + lrow;
                a[fr] = *reinterpret_cast<const v8s*>(
                    &As[r * 64 + ((k0 + quad * 8) ^ ((r & 7) * 8))]);
            }
#pragma unroll
            for (int fc = 0; fc < FC; ++fc) {
                int r = cbase + fc * 16 + lrow;
                b[fc] = *reinterpret_cast<const v8s*>(
                    &Bs[r * 64 + ((k0 + quad * 8) ^ ((r & 7) * 8))]);
            }
#pragma unroll
            for (int fr = 0; fr < FR; ++fr)
#pragma unroll
                for (int fc = 0; fc < FC; ++fc)
                    acc[fr][fc] = __builtin_amdgcn_mfma_f32_16x16x32_bf16(a[fr], b[fc], acc[fr][fc], 0, 0, 0);
        }
        __syncthreads();
    }

    // epilogue: C/D layout col=lane&15, row=quad*4+reg  [m89-verified]
    bf16* outBz = outB ? outB + (size_t)z * oZOff : nullptr;
#pragma unroll
    for (int fr = 0; fr < FR; ++fr) {
#pragma unroll
        for (int fc = 0; fc < FC; ++fc) {
            int ncol = n0 + cbase + fc * 16 + lrow;
            float bi = bias ? ldin(bias, ncol, f32) : 0.f;
            bool doflip = (ncol >= flipN0) || (zflip && z == 1);
#pragma unroll
            for (int r = 0; r < 4; ++r) {
                int m = m0 + rbase + fr * 16 + quad * 4 + r;
                float vv = acc[fr][fc][r] + bi;
                if (act == 2) vv = 0.5f * vv * (1.f + erff(vv * 0.70710678118654752440f));
                if (resid) vv += resid[(size_t)m * ldo + ncol];
                if (outCcp && ncol >= nSplit2) {
                    float v2 = vv + ldin(ccpBias, ncol - nSplit2, f32);
                    outCcp[(size_t)m * kD + (ncol - nSplit2)] = __float2bfloat16(v2);
                } else if (outSplitZ) {
                    int dir = (ncol >> 11) & 1;
                    int isz = (ncol >> 10) & 1;
                    int c2 = dir * 1024 + (ncol & 1023);
                    int mo_ = dir ? flipL(m) : m;
                    bf16* dst = isz ? outSplitZ : outB;
                    dst[(size_t)mo_ * 2048 + c2] = __float2bfloat16(vv);
                } else {
                    int mo_ = doflip ? flipL(m) : m;
                    size_t oi = (size_t)mo_ * ldo + ncol;
                    if (outBz) outBz[oi] = __float2bfloat16(vv);
                    else if (f32) ((float*)outRaw)[oi] = vv;
                    else ((bf16*)outRaw)[oi] = __float2bfloat16(vv);
                }
            }
        }
    }
}

// ---------------- depthwise causal conv + silu, both dirs ----------------
__global__ __launch_bounds__(256) void conv_kernel(const bf16* __restrict__ xp,
                                                   const void* __restrict__ cw_f,
                                                   const void* __restrict__ cb_f,
                                                   const void* __restrict__ cw_b,
                                                   const void* __restrict__ cb_b,
                                                   bf16* __restrict__ xc,
                                                   const int* __restrict__ flg) {
    int f32 = *flg;
    int tid = blockIdx.x * 256 + threadIdx.x;  // 2*kM*kDI
    int d = tid & (kDI - 1);
    int r = (tid >> 10) & (kM - 1);
    int dir = tid >> 21;
    int l = r & (kL - 1);
    int b = r >> 10;
    const void* cw = dir ? cw_b : cw_f;
    const void* cb = dir ? cb_b : cb_f;
    float acc = ldin(cb, d, f32);
#pragma unroll
    for (int k = 0; k < kKC; ++k) {
        int ll = l - (kKC - 1) + k;
        if (ll >= 0)
            acc += ldin(cw, d * kKC + k, f32) *
                   toF(xp[(size_t)(b * kL + ll) * (2 * kDI) + dir * kDI + d]);
    }
    float s = acc / (1.f + __expf(-acc));
    xc[(size_t)r * (2 * kDI) + dir * kDI + d] = __float2bfloat16(s);
}

// ---------------- delta precompute: dl = softplus(dt @ wdt^T + dtb) ----------------
// xdbl: (2048 x 128) = [dt_f(32)|B_f(16)|C_f(16) | dt_b|B_b|C_b]
__global__ __launch_bounds__(256) void delta_kernel(const bf16* __restrict__ xdbl,
                                                    const bf16* __restrict__ wdt,
                                                    const void* __restrict__ dtb_f,
                                                    const void* __restrict__ dtb_b,
                                                    __half* __restrict__ deltaH,
                                                    const int* __restrict__ flg) {
    __shared__ float arow[kDTR];
    int f32 = *flg;
    int m = blockIdx.y;    // b*L + l
    int dir = blockIdx.z;
    int d = blockIdx.x * 256 + threadIdx.x;
    if (threadIdx.x < kDTR)
        arow[threadIdx.x] = toF(xdbl[(size_t)m * 128 + dir * 64 + threadIdx.x]);
    __syncthreads();
    float acc = ldin(dir ? dtb_b : dtb_f, d, f32);
    const v8s* wv = reinterpret_cast<const v8s*>(wdt + ((size_t)dir * kDI + d) * kDTR);
#pragma unroll
    for (int t = 0; t < 4; ++t) {
        v8s w8 = wv[t];
#pragma unroll
        for (int k = 0; k < 8; ++k) acc += arow[t * 8 + k] * b2f(w8[k]);
    }
    acc = (acc > 20.f) ? acc : log1pf(__expf(acc));
    deltaH[((size_t)dir * kM + m) * kDI + d] = __float2half(acc);
}

// ---------------- fused local scan: y_local + chunk summaries + cumsum(dl) ----------------
// tid bits: [1:0]=n4, [11:2]=d, [16:12]=c, [17]=b, [18]=dir  (524288 threads)
// PA/HLh layout is d-innermost: [((g*kCH + c)*kNS + n)*kDI + d], g = dir*2+b.
__global__ __launch_bounds__(256) void scan_phase1(const bf16* __restrict__ xc,
                                                   const bf16* __restrict__ xdbl,
                                                   __half* __restrict__ deltaS,
                                                   const float* __restrict__ anT,
                                                   float* __restrict__ PA,
                                                   __half* __restrict__ HLh,
                                                   bf16* __restrict__ ymul,
                                                   const int* __restrict__ flg) {
    int tid = blockIdx.x * 256 + threadIdx.x;
    int n4  = tid & 3;
    int d   = (tid >> 2) & (kDI - 1);
    int c   = (tid >> 12) & (kCH - 1);
    int b   = (tid >> 17) & 1;
    int dir = tid >> 18;
    float an[4], h[4], pa[4];
#pragma unroll
    for (int j = 0; j < 4; ++j) {
        an[j] = anT[((size_t)dir * kNS + n4 * 4 + j) * kDI + d];
        h[j] = 0.f;
        pa[j] = 1.f;
    }
    __half* dptr = deltaS + ((size_t)dir * kM + (size_t)b * kL) * kDI + d;
    float s = 0.f;
    int l0 = c * kCL;
    for (int l = l0; l < l0 + kCL; ++l) {
        size_t rb = (size_t)b * kL + l;
        float dl = __half2float(dptr[(size_t)l * kDI]);
        s += dl;
        float xcv = toF(xc[rb * (2 * kDI) + dir * kDI + d]);
        float du = dl * xcv;
        v4s Bv = *reinterpret_cast<const v4s*>(xdbl + rb * 128 + dir * 64 + kDTR + n4 * 4);
        v4s Cv = *reinterpret_cast<const v4s*>(xdbl + rb * 128 + dir * 64 + kDTR + kNS + n4 * 4);
        float yp = 0.f;
#pragma unroll
        for (int j = 0; j < 4; ++j) {
            float a = __expf(dl * an[j]);
            pa[j] *= a;
            h[j] = a * h[j] + du * b2f(Bv[j]);
            yp += h[j] * b2f(Cv[j]);
        }
        yp += __shfl_xor(yp, 1);
        yp += __shfl_xor(yp, 2);
        if (n4 == 0) {
            ymul[rb * (2 * kDI) + dir * kDI + d] = __float2bfloat16(yp);
            dptr[(size_t)l * kDI] = __float2half(s);  // in-place: all lanes read dl above first
        }
    }
    int g = dir * kB + b;
    size_t o = (((size_t)g * kCH + c) * kNS + n4 * 4) * kDI + d;
#pragma unroll
    for (int j = 0; j < 4; ++j) {
        PA[o + (size_t)j * kDI] = pa[j];
        HLh[o + (size_t)j * kDI] = __float2half(h[j]);
    }
}

// combine over chunks; write HIN (incoming state per chunk) in-place into PA
// tid bits: [9:0]=d, [13:10]=n, [15:14]=g  (65536 threads) — d-innermost -> coalesced
__global__ __launch_bounds__(256) void scan_phase2(float* __restrict__ PA,
                                                   const __half* __restrict__ HLh) {
    int tid = blockIdx.x * 256 + threadIdx.x;
    int d = tid & (kDI - 1);
    int n = (tid >> 10) & (kNS - 1);
    int g = tid >> 14;
    float h = 0.f;
    for (int c = 0; c < kCH; ++c) {
        size_t idx = (((size_t)g * kCH + c) * kNS + n) * kDI + d;
        float pav = PA[idx];
        float hlv = __half2float(HLh[idx]);
        PA[idx] = h;  // HIN for chunk c
        h = pav * h + hlv;
    }
}

// ---------------- parallel correction: y = y_local + C.(exp(an*s) * h_in) + xc*D, gate silu(z) ----------------
// tid bits: [9:0]=d, [19:10]=l, [20]=b, [21]=dir  (4,194,304 threads)
__global__ __launch_bounds__(256) void scan_fix(const bf16* __restrict__ xc,
                                                const bf16* __restrict__ xdbl,
                                                const bf16* __restrict__ zb,
                                                const __half* __restrict__ sbuf,
                                                const float* __restrict__ anT,
                                                const void* __restrict__ dp_f,
                                                const void* __restrict__ dp_b,
                                                const float* __restrict__ HIN,
                                                bf16* __restrict__ ymul,
                                                const int* __restrict__ flg) {
    int f32 = *flg;
    int tid = blockIdx.x * 256 + threadIdx.x;
    int d   = tid & (kDI - 1);
    int l   = (tid >> 10) & (kL - 1);
    int b   = (tid >> 20) & 1;
    int dir = tid >> 21;
    int c   = l / kCL;
    size_t rb = (size_t)b * kL + l;
    float s = __half2float(sbuf[((size_t)dir * kM + rb) * kDI + d]);
    int g = dir * kB + b;
    const float* hin = HIN + (((size_t)g * kCH + c) * kNS) * kDI + d;
    const float* anp = anT + (size_t)dir * kNS * kDI + d;
    const bf16* Cp = xdbl + rb * 128 + dir * 64 + kDTR + kNS;
    float ycorr = 0.f;
#pragma unroll
    for (int n = 0; n < kNS; ++n) {
        float an = anp[(size_t)n * kDI];
        ycorr += toF(Cp[n]) * __expf(an * s) * hin[(size_t)n * kDI];
    }
    size_t yi = rb * (2 * kDI) + dir * kDI + d;
    float xcv = toF(xc[yi]);
    float Dv = ldin(dir ? dp_b : dp_f, d, f32);
    float y = toF(ymul[yi]) + ycorr + xcv * Dv;
    float zv = toF(zb[yi]);
    float sz = zv / (1.f + __expf(-zv));
    ymul[yi] = __float2bfloat16(y * sz);
}

// ---------------- fused context-cluster + gate + residual + FFN-LN ----------------
__global__ __launch_bounds__(256) void post_kernel(const bf16* __restrict__ proj,
                                                   const void* __restrict__ centers,
                                                   const float* __restrict__ cn,
                                                   const bf16* __restrict__ xn,
                                                   const void* __restrict__ alpha_p,
                                                   const void* __restrict__ ccg,
                                                   const void* __restrict__ ccb,
                                                   const void* __restrict__ X,
                                                   const bf16* __restrict__ mo,
                                                   const void* __restrict__ gw,
                                                   const void* __restrict__ gb,
                                                   const void* __restrict__ fg,
                                                   const void* __restrict__ fbb,
                                                   float* __restrict__ xmid,
                                                   bf16* __restrict__ hln,
                                                   const int* __restrict__ flg) {
    __shared__ float sred[8];
    __shared__ float sims[kNC];
    int f32 = *flg;
    int row = blockIdx.x;
    int i = threadIdx.x;
    size_t base = (size_t)row * kD;
    float p0 = toF(proj[base + i]), p1 = toF(proj[base + i + 256]);
    float sumsq = blockReduceSum(p0 * p0 + p1 * p1, sred);
    float pn = fmaxf(sqrtf(sumsq), 1e-12f);
    for (int c = 0; c < kNC; ++c) {
        float part = p0 * ldin(centers, c * kD + i, f32) + p1 * ldin(centers, c * kD + i + 256, f32);
        float dot = blockReduceSum(part, sred);
        if (threadIdx.x == 0) sims[c] = dot / (pn * fmaxf(cn[c], 1e-12f));
    }
    __syncthreads();
    float mx = -1e30f;
#pragma unroll
    for (int c = 0; c < kNC; ++c) mx = fmaxf(mx, sims[c]);
    float wv[kNC], se = 0.f;
#pragma unroll
    for (int c = 0; c < kNC; ++c) { wv[c] = __expf(sims[c] - mx); se += wv[c]; }
    float inv = 1.f / se;
    float ctx0 = 0.f, ctx1 = 0.f;
#pragma unroll
    for (int c = 0; c < kNC; ++c) {
        float wc = wv[c] * inv;
        ctx0 += wc * ldin(centers, c * kD + i, f32);
        ctx1 += wc * ldin(centers, c * kD + i + 256, f32);
    }
    float alpha = ldin(alpha_p, 0, f32);
    float x0 = toF(xn[base + i]), x1 = toF(xn[base + i + 256]);
    float t0 = x0 + alpha * ctx0;
    float t1 = x1 + alpha * ctx1;
    float mean = blockReduceSum(t0 + t1, sred) * (1.f / kD);
    float vs = blockReduceSum(t0 * t0 + t1 * t1, sred) * (1.f / kD) - mean * mean;
    float rstd = rsqrtf(vs + kEPS);
    float cc0 = (t0 - mean) * rstd * ldin(ccg, i, f32)       + ldin(ccb, i, f32);
    float cc1 = (t1 - mean) * rstd * ldin(ccg, i + 256, f32) + ldin(ccb, i + 256, f32);
    // gate
    float d0 = blockReduceSum(x0 * ldin(gw, i, f32) + x1 * ldin(gw, i + 256, f32), sred);
    float d1 = blockReduceSum(x0 * ldin(gw, kD + i, f32) + x1 * ldin(gw, kD + i + 256, f32), sred);
    d0 += ldin(gb, 0, f32);
    d1 += ldin(gb, 1, f32);
    float gmx = fmaxf(d0, d1);
    float e0 = __expf(d0 - gmx), e1 = __expf(d1 - gmx);
    float gs = e0 + e1;
    float g0 = e0 / gs, g1 = e1 / gs;
    float xm0 = ldin(X, base + i, f32)       + g0 * toF(mo[base + i])       + g1 * cc0;
    float xm1 = ldin(X, base + i + 256, f32) + g0 * toF(mo[base + i + 256]) + g1 * cc1;
    xmid[base + i] = xm0;
    xmid[base + i + 256] = xm1;
    // FFN LayerNorm
    float mean2 = blockReduceSum(xm0 + xm1, sred) * (1.f / kD);
    float vs2 = blockReduceSum(xm0 * xm0 + xm1 * xm1, sred) * (1.f / kD) - mean2 * mean2;
    float rstd2 = rsqrtf(vs2 + kEPS);
    hln[base + i]       = __float2bfloat16((xm0 - mean2) * rstd2 * ldin(fg, i, f32)       + ldin(fbb, i, f32));
    hln[base + i + 256] = __float2bfloat16((xm1 - mean2) * rstd2 * ldin(fg, i + 256, f32) + ldin(fbb, i + 256, f32));
}

// ---------------- launch ----------------
extern "C" void kernel_launch(void* const* d_in, const int* in_sizes, int n_in,
                              void* d_out, int out_size, void* d_ws, size_t ws_size,
                              hipStream_t stream) {
    bool sig = (n_in > 3 && in_sizes[3] == 2 * kDI * kD);
    int I_fusion_w = sig ? 21 : 3,  I_fusion_b = sig ? 22 : 4;
    int I_centers  = sig ? 23 : 5,  I_ccp_w    = sig ? 24 : 6,  I_ccp_b = sig ? 25 : 7;
    int I_ccn_g    = sig ? 26 : 8,  I_ccn_b    = sig ? 27 : 9,  I_alpha = sig ? 28 : 10;
    int I_gate_w   = sig ? 29 : 11, I_gate_b   = sig ? 30 : 12;
    int I_ffn_g    = sig ? 31 : 13, I_ffn_b    = sig ? 32 : 14;
    int I_ffn_w1   = sig ? 33 : 15, I_ffn_b1   = sig ? 34 : 16;
    int I_ffn_w2   = sig ? 35 : 17, I_ffn_b2   = sig ? 36 : 18;
    int I_fm       = sig ? 3  : 19, I_bm       = sig ? 12 : 28;

    const void* X        = d_in[0];
    const void* n1g      = d_in[1];
    const void* n1b      = d_in[2];
    const void* fusion_b = d_in[I_fusion_b];
    const void* centers  = d_in[I_centers];
    const void* ccp_b    = d_in[I_ccp_b];
    const void* ccn_g    = d_in[I_ccn_g];
    const void* ccn_b    = d_in[I_ccn_b];
    const void* cc_alpha = d_in[I_alpha];
    const void* gate_w   = d_in[I_gate_w];
    const void* gate_b   = d_in[I_gate_b];
    const void* ffn_g    = d_in[I_ffn_g];
    const void* ffn_b    = d_in[I_ffn_b];
    const void* ffn_b1   = d_in[I_ffn_b1];
    const void* ffn_b2   = d_in[I_ffn_b2];

    // ---- workspace layout (float units) — total ~63.4 MB ----
    float* ws = (float*)d_ws;
    int* flg  = (int*)d_ws;           // ws[0]
    float* cn = ws + 8;               // 8 floats
    float*  anT  = ws + 32;                          // 32,768 f  (2 x 16 x 1024)
    float*  PA   = anT + 32768;                      // 2,097,152 f (d-innermost chunk summaries -> HIN)
    __half* HLh  = (__half*)(PA + 2097152);          // 2,097,152 half = 1,048,576 f
    bf16*  xn   = (bf16*)((float*)HLh + 1048576);    // 2048x512 bf16   = 524,288 f
    bf16*  xp   = (bf16*)((float*)xn + 524288);      // 2048x2048 bf16  = 2,097,152 f
    bf16*  zb   = (bf16*)((float*)xp + 2097152);     // 2048x2048 bf16  = 2,097,152 f
    bf16*  xc   = (bf16*)((float*)zb + 2097152);     // 2048x2048 bf16  = 2,097,152 f
    bf16*  xdbl = (bf16*)((float*)xc + 2097152);     // 2048x128 bf16   = 131,072 f
    bf16*  ymul = (bf16*)((float*)xdbl + 131072);    // 2048x2048 bf16  = 2,097,152 f
    bf16*  wbuf = (bf16*)((float*)ymul + 2097152);   // 6,225,920 bf16  = 3,112,960 f
    bf16*  projb = (bf16*)((float*)wbuf + 3112960);  // 2048x512 bf16   = 524,288 f (dedicated)
    // aliases of dead regions (size-checked):
    __half* deltaH = (__half*)xp;    // 4,194,304 half exact (xp dead after conv); becomes s(l) after phase1
    bf16*  fb    = (bf16*)HLh;       // 2,097,152 bf16 exact (HLh dead after phase2; out_proj writes later)
    bf16*  mo    = (bf16*)PA;        // 524,288 f <= PA (HIN dead after scan_fix; fusion writes later)
    float* xmid  = PA + 524288;      // 1,048,576 f, disjoint from mo, within PA region (2M)
    bf16*  hln   = xc;               // after scan_fix
    bf16*  ffnh  = zb;               // after scan_fix (2M f exact)

    // weight views (order: fm_in, bm_in, fm_xproj, bm_xproj, fm_dt, bm_dt, fm_out, bm_out, fusion, ccp, ffn1, ffn2)
    bf16* w_in     = wbuf + 0;        // [fm|bm] concat, N=4096 x K=512
    bf16* w_xp     = wbuf + 2097152;  // 2 x (64 x 1024)
    bf16* w_dt     = wbuf + 2228224;  // 2 x (1024 x 32)
    bf16* w_out    = wbuf + 2293760;  // 2 x (512 x 1024)
    bf16* w_fusion = wbuf + 3342336;
    bf16* w_ccp    = wbuf + 3866624;
    bf16* w_ffn1   = wbuf + 4128768;
    bf16* w_ffn2   = wbuf + 5177344;

    dim3 blk(256);
    constexpr int NOFLIP = 1 << 30;

    WSrcs srcs;
    srcs.p[0] = d_in[I_fm + 0]; srcs.p[1] = d_in[I_bm + 0];
    srcs.p[2] = d_in[I_fm + 3]; srcs.p[3] = d_in[I_bm + 3];
    srcs.p[4] = d_in[I_fm + 4]; srcs.p[5] = d_in[I_bm + 4];
    srcs.p[6] = d_in[I_fm + 8]; srcs.p[7] = d_in[I_bm + 8];
    srcs.p[8] = d_in[I_fusion_w]; srcs.p[9] = d_in[I_ccp_w];
    srcs.p[10] = d_in[I_ffn_w1]; srcs.p[11] = d_in[I_ffn_w2];

    // fused setup: weight conversion + anT + center norms + dtype flag + input LN
    setup_kernel<<<dim3(512, 17), blk, 0, stream>>>(
        srcs, wbuf, d_in[I_fm + 6], d_in[I_bm + 6], centers, anT, cn, flg,
        X, n1g, n1b, xn);

    // in_proj both dirs + ccp merged: N = 4096 (split xp/zb) + 512 (projb).
    // 64x64 tiles, gridSwap: m fastest -> consecutive blocks share weight tile, xn L2-resident.
    mfma_gemm<64, 64, 2, 2><<<dim3(32, 72, 1), blk, 0, stream>>>(
        xn, kD, 0, w_in, kD, 0, nullptr, 0, nullptr, xp, nullptr, 2048, 0, NOFLIP, 0, flg, zb,
        w_ccp, ccp_b, projb, 4096, 1);

    // conv both dirs
    conv_kernel<<<2 * kM * kDI / 256, blk, 0, stream>>>(
        xp, d_in[I_fm + 1], d_in[I_fm + 2], d_in[I_bm + 1], d_in[I_bm + 2], xc, flg);

    // xproj both dirs: z-batched MFMA (N=64, K=1024), 32x64 tiles
    mfma_gemm<32, 64, 1, 4><<<dim3(1, 64, 2), blk, 0, stream>>>(
        xc, 2 * kDI, kDI, w_xp, kDI, 65536, nullptr, 0, nullptr, xdbl, nullptr, 128, 64,
        NOFLIP, 0, flg, nullptr, nullptr, nullptr, nullptr, NOFLIP, 0);

    // delta precompute (xp dead -> deltaH aliases it)
    delta_kernel<<<dim3(kDI / 256, kM, 2), blk, 0, stream>>>(
        xdbl, w_dt, d_in[I_fm + 5], d_in[I_bm + 5], deltaH, flg);

    // fused local scan (single sequential pass) + chunk combine + parallel correction
    scan_phase1<<<2048, blk, 0, stream>>>(xc, xdbl, deltaH, anT, PA, HLh, ymul, flg);
    scan_phase2<<<256, blk, 0, stream>>>(PA, HLh);
    scan_fix<<<16384, blk, 0, stream>>>(xc, xdbl, zb, deltaH, anT,
                                        d_in[I_fm + 7], d_in[I_bm + 7], PA, ymul, flg);

    // out_proj both dirs: z-batched; z=1 (bm) rows flipped back; 32x64 tiles -> 1024 blocks
    mfma_gemm<32, 64, 1, 4><<<dim3(8, 64, 2), blk, 0, stream>>>(
        ymul, 2 * kDI, kDI, w_out, kDI, 524288, nullptr, 0, nullptr, fb, nullptr, 2 * kD, kD,
        NOFLIP, 1, flg, nullptr, nullptr, nullptr, nullptr, NOFLIP, 0);

    // mamba_out = fb @ fusion_w^T + fusion_b  (32x64 tiles -> 512 blocks)
    mfma_gemm<32, 64, 1, 4><<<dim3(8, 64, 1), blk, 0, stream>>>(
        fb, 2 * kD, 0, w_fusion, 2 * kD, 0, fusion_b, 0, nullptr, mo, nullptr, kD, 0,
        NOFLIP, 0, flg, nullptr, nullptr, nullptr, nullptr, NOFLIP, 0);

    // fused cc + gate + residual + FFN-LN
    post_kernel<<<kM, blk, 0, stream>>>(projb, centers, cn, xn, cc_alpha, ccn_g, ccn_b,
                                        X, mo, gate_w, gate_b, ffn_g, ffn_b, xmid, hln, flg);

    // FFN1: 64x64, gridSwap (m fastest; hln 2MB L2-resident)
    mfma_gemm<64, 64, 2, 2><<<dim3(32, 32, 1), blk, 0, stream>>>(
        hln, kD, 0, w_ffn1, kD, 0, ffn_b1, 2, nullptr, ffnh, nullptr, 4 * kD, 0, NOFLIP, 0, flg,
        nullptr, nullptr, nullptr, nullptr, NOFLIP, 1);
    mfma_gemm<32, 64, 1, 4><<<dim3(8, 64, 1), blk, 0, stream>>>(
        ffnh, 4 * kD, 0, w_ffn2, 4 * kD, 0, ffn_b2, 0, xmid, nullptr, d_out, kD, 0,
        NOFLIP, 0, flg, nullptr, nullptr, nullptr, nullptr, NOFLIP, 0);
}